// Round 6
// baseline (342.549 us; speedup 1.0000x reference)
//
#include <hip/hip_runtime.h>

typedef __attribute__((ext_vector_type(8))) __bf16 bf16x8;
typedef __attribute__((ext_vector_type(4))) float f32x4;
typedef __attribute__((ext_vector_type(4))) float f4;
typedef __attribute__((ext_vector_type(4))) unsigned short ushort4_t;

__device__ inline void gload16(const void* g, void* l) {
  __builtin_amdgcn_global_load_lds(
      (const __attribute__((address_space(1))) unsigned int*)g,
      (__attribute__((address_space(3))) unsigned int*)l, 16, 0, 0);
}

// ---------------------------------------------------------------- converts
__global__ void convert_bf16_k(const float* __restrict__ in, __bf16* __restrict__ out, int n8) {
  int i = blockIdx.x * blockDim.x + threadIdx.x;
  int stride = gridDim.x * blockDim.x;
  for (; i < n8; i += stride) {
    f4 a = ((const f4*)in)[2 * (long long)i];
    f4 b = ((const f4*)in)[2 * (long long)i + 1];
    bf16x8 o;
#pragma unroll
    for (int e = 0; e < 4; e++) { o[e] = (__bf16)a[e]; o[e + 4] = (__bf16)b[e]; }
    ((bf16x8*)out)[i] = o;
  }
}

__global__ void pack_bias_k(const float* __restrict__ bq, const float* __restrict__ bk,
                            const float* __restrict__ bv, float* __restrict__ out) {
  int i = blockIdx.x * 256 + threadIdx.x;
  if (i >= 3072) return;
  const float* src = (i < 1024) ? bq : (i < 2048) ? bk : bv;
  out[i] = src[i & 1023];
}

// W[k][n] fp32 -> Wt[n][k] bf16, 4 weights via z
__global__ void transpose_w_k(const float* __restrict__ W0, const float* __restrict__ W1,
                              const float* __restrict__ W2, const float* __restrict__ W3,
                              __bf16* __restrict__ out) {
  int z = blockIdx.z;
  const float* W = (z == 0) ? W0 : (z == 1) ? W1 : (z == 2) ? W2 : W3;
  __bf16* O = out + (long long)z * 1048576;
  __shared__ float tile[32][33];
  int tx = threadIdx.x, ty = threadIdx.y;
  int n0 = blockIdx.x * 32, k0 = blockIdx.y * 32;
#pragma unroll
  for (int i = 0; i < 4; i++)
    tile[ty + i * 8][tx] = W[(long long)(k0 + ty + i * 8) * 1024 + n0 + tx];
  __syncthreads();
#pragma unroll
  for (int i = 0; i < 4; i++)
    O[(long long)(n0 + ty + i * 8) * 1024 + k0 + tx] = (__bf16)tile[tx][ty + i * 8];
}

// ---------------------------------------------------------------- gemm8: 256x256 tile, BK=64, 8-phase
// (round-4 form: full-kt loop, monolithic epilogue). Used for QKV + out-proj.
// LDS 160 KiB: A triple-buffered + B double-buffered, XOR-swizzled (row&7)<<4.
// A(kk+2) issued during tile kk; B(kk+2) overwrites-behind. ENDPB vmcnt(8).
// OUT: 0 = bf16 C, 1 = f32 C,
//      2 = fused QKV z-routing: z<2 -> scalar bf16 C; z==2 -> V LDS-transposed
//          coalesced into vt_out[b][d][t].
// SWZ: 0 = generic bijective XCD swizzle; 1 = A-stripe (br fastest, bc, z slowest)

#define LOADA(BASE, MIB)                                                       \
  _Pragma("unroll") for (int mi = 0; mi < 4; mi++)                             \
      _Pragma("unroll") for (int kh = 0; kh < 2; kh++) {                       \
    int row = ((MIB) + mi) * 16 + ln15;                                        \
    int pb = (row * 128 + (kh * 32 + kq * 8) * 2) ^ ((row & 7) << 4);          \
    a[mi][kh] = *(const bf16x8*)((BASE) + pb);                                 \
  }

#define LOADB(BASE, NIB)                                                       \
  _Pragma("unroll") for (int ni = 0; ni < 2; ni++)                             \
      _Pragma("unroll") for (int kh = 0; kh < 2; kh++) {                       \
    int row = brow0 + ((NIB) + ni) * 16 + ln15;                                \
    int pb = (row * 128 + (kh * 32 + kq * 8) * 2) ^ ((row & 7) << 4);          \
    b[(NIB) + ni][kh] = *(const bf16x8*)((BASE) + pb);                         \
  }

#define MFMAQ(MI0, NI0)                                                        \
  _Pragma("unroll") for (int mi = 0; mi < 4; mi++)                             \
      _Pragma("unroll") for (int ni = 0; ni < 2; ni++)                         \
          _Pragma("unroll") for (int kh = 0; kh < 2; kh++)                     \
              acc[(MI0) + mi][(NI0) + ni] =                                    \
      __builtin_amdgcn_mfma_f32_16x16x32_bf16(a[mi][kh], b[(NI0) + ni][kh],    \
                                              acc[(MI0) + mi][(NI0) + ni], 0, 0, 0);

#define FENCE asm volatile("" ::: "memory")

#define BARW                                           \
  FENCE;                                               \
  __builtin_amdgcn_s_barrier();                        \
  FENCE;                                               \
  __builtin_amdgcn_s_setprio(1);

#define ENDP                                           \
  __builtin_amdgcn_s_setprio(0);                       \
  FENCE;                                               \
  __builtin_amdgcn_s_barrier();                        \
  FENCE;

#define ENDPB                                          \
  __builtin_amdgcn_s_setprio(0);                       \
  asm volatile("s_waitcnt vmcnt(8)" ::: "memory");     \
  __builtin_amdgcn_s_barrier();                        \
  FENCE;

template <int OUT, int SWZ>
__global__ __launch_bounds__(512, 2) void gemm8(
    const __bf16* __restrict__ A0, int lda, long long sAz,
    const __bf16* __restrict__ B0, int ldb, long long sBz,
    void* __restrict__ C0v, int ldc, long long sCz,
    const float* __restrict__ bias0, int sBiasZ,
    float scale_z0, int k_tiles_base, int k_tiles_per_br,
    __bf16* __restrict__ vt_out) {
  int br, bc, z;
  {
    const int lin = (blockIdx.z * gridDim.y + blockIdx.y) * gridDim.x + blockIdx.x;
    if (SWZ == 1) {
      // A-stripe: XCD q -> br in [8q,8q+8), br fastest; then bc; then z.
      const int q = lin & 7, c = lin >> 3;
      br = q * 8 + (c & 7);
      const int rest = c >> 3;
      const int nby = gridDim.y;
      bc = rest % nby;
      z = rest / nby;
    } else {
      const int nbx = gridDim.x, nby = gridDim.y;
      const int nwg = nbx * nby * gridDim.z;
      const int cpx = nwg >> 3;
      const int swz = (lin & 7) * cpx + (lin >> 3);
      br = swz % nbx;
      const int tmp = swz / nbx;
      bc = tmp % nby;
      z = tmp / nby;
    }
  }
  const int kt = k_tiles_base + k_tiles_per_br * br;  // >= 2

  // 160 KiB LDS: A bufs at 0,16384,32768 (elems); B bufs at 49152,65536
  __shared__ __align__(16) __bf16 lds[81920];

  const int t = threadIdx.x, w = t >> 6, lane = t & 63;
  const int wm = w >> 2, wn = w & 3;
  const int ln15 = lane & 15, kq = lane >> 4;
  const int bh = wn >> 1, brow0 = (wn & 1) * 64;

  const __bf16* A = A0 + (long long)z * sAz + (long long)br * 256 * lda;
  const __bf16* B = B0 + (long long)z * sBz + (long long)bc * 256 * ldb;

  // pre-swizzled staging source coords (physical->logical, involution)
  int r0s[2], c0s[2];
#pragma unroll
  for (int i = 0; i < 2; i++) {
    int o = i * 8192 + t * 16;
    int lo = o ^ (((o >> 7) & 7) << 4);
    r0s[i] = lo >> 7;
    c0s[i] = (lo & 127) >> 1;
  }
  const __bf16 *sA0[2], *sA1[2], *sB0[2], *sB1[2];
#pragma unroll
  for (int i = 0; i < 2; i++) {
    sA0[i] = A + (long long)r0s[i] * lda + c0s[i];
    sA1[i] = A + (long long)(r0s[i] + 128) * lda + c0s[i];
    sB0[i] = B + (long long)r0s[i] * ldb + c0s[i];
    sB1[i] = B + (long long)(r0s[i] + 128) * ldb + c0s[i];
  }

  auto stg = [&](const __bf16* const* src, __bf16* lbase, int g) {
    int kc = g < kt ? g : kt - 1;  // clamped dup keeps per-iter issue count = 8
#pragma unroll
    for (int i = 0; i < 2; i++)
      gload16(src[i] + kc * 64, lbase + i * 4096 + w * 512);
  };

  f32x4 acc[8][4] = {};
  bf16x8 a[4][2], b[4][2];

  // prologue: A(0),B(0),A(1),B(1); wait oldest 8 -> A(0),B(0) resident
  stg(sA0, lds, 0);
  stg(sA1, lds + 8192, 0);
  stg(sB0, lds + 49152, 0);
  stg(sB1, lds + 49152 + 8192, 0);
  stg(sA0, lds + 16384, 1);
  stg(sA1, lds + 16384 + 8192, 1);
  stg(sB0, lds + 65536, 1);
  stg(sB1, lds + 65536 + 8192, 1);
  asm volatile("s_waitcnt vmcnt(8)" ::: "memory");
  __builtin_amdgcn_s_barrier();
  FENCE;

  int ap = 0;   // A buffer index of tile kk (mod 3)
  int ad = 2;   // A buffer index of tile kk+2
  for (int kk = 0; kk < kt; kk++) {
    __bf16* Ab = lds + ap * 16384;
    __bf16* Bb = lds + 49152 + (kk & 1) * 16384;
    __bf16* Ad = lds + ad * 16384;
    __bf16* Bd = Bb;  // B(kk+2) overwrites-behind
    const char* Aw = (const char*)(Ab + wm * 8192);
    const char* Bw = (const char*)(Bb + bh * 8192);
    LOADA(Aw, 0) LOADB(Bw, 0)
    stg(sA0, Ad, kk + 2);
    BARW MFMAQ(0, 0) ENDP
    LOADB(Bw, 2)
    stg(sA1, Ad + 8192, kk + 2);
    BARW MFMAQ(0, 2) ENDP
    LOADA(Aw, 4)
    stg(sB0, Bd, kk + 2);
    BARW MFMAQ(4, 2) ENDP
    stg(sB1, Bd + 8192, kk + 2);
    BARW MFMAQ(4, 0) ENDPB
    ap = (ap == 2) ? 0 : ap + 1;
    ad = (ad == 2) ? 0 : ad + 1;
  }

  // ---- epilogue ----
  if (OUT == 2 && z == 2) {
    // V: stage 256x256 tile into LDS as [d][t] (XOR-swizzled), then coalesced
    // 16B row stores into vt_out[b][d][t].
    __syncthreads();
    char* lb = (char*)lds;
    const int dl0 = wn * 64 + ln15;
    const int tl0 = wm * 128 + kq * 4;
#pragma unroll
    for (int mi = 0; mi < 8; mi++) {
#pragma unroll
      for (int ni = 0; ni < 4; ni++) {
        const int d = dl0 + ni * 16;
        const int tl = tl0 + mi * 16;
        const float bb = bias0[2048 + bc * 256 + d];
        ushort4_t p;
#pragma unroll
        for (int j = 0; j < 4; j++) {
          union { __bf16 h; unsigned short u; } cv;
          cv.h = (__bf16)(acc[mi][ni][j] + bb);
          p[j] = cv.u;
        }
        int byte = d * 512 + tl * 2;
        byte ^= (d & 7) << 4;
        *(ushort4_t*)(lb + byte) = p;
      }
    }
    __syncthreads();
    const int bz = br >> 3;
    __bf16* vbase = vt_out + (long long)bz * 2097152 +
                    (long long)(bc * 256) * 2048 + (br & 7) * 256;
#pragma unroll
    for (int it = 0; it < 16; it++) {
      int idx = it * 512 + t;
      int d = idx >> 5, tc = idx & 31;
      int byte = d * 512 + tc * 16;
      byte ^= (d & 7) << 4;
      bf16x8 vv = *(const bf16x8*)(lb + byte);
      *(bf16x8*)(vbase + (long long)d * 2048 + tc * 8) = vv;
    }
  } else {
    const int row0 = br * 256 + wm * 128 + kq * 4;
    const int col0 = bc * 256 + wn * 64 + ln15;
    const float scale = (z == 0) ? scale_z0 : 1.0f;
    const float* bias = bias0 ? (bias0 + (long long)z * sBiasZ) : nullptr;
#pragma unroll
    for (int mi = 0; mi < 8; mi++) {
#pragma unroll
      for (int ni = 0; ni < 4; ni++) {
        const int rr = row0 + mi * 16;
        const int cc = col0 + ni * 16;
        const float bb = bias ? bias[cc] : 0.0f;
#pragma unroll
        for (int j = 0; j < 4; j++) {
          float v = (acc[mi][ni][j] + bb) * scale;
          long long off = (long long)z * sCz + (long long)(rr + j) * ldc + cc;
          if (OUT == 1)
            ((float*)C0v)[off] = v;
          else
            ((__bf16*)C0v)[off] = (__bf16)v;
        }
      }
    }
  }
}

// ---------------------------------------------------------------- gemm4: 128x128 tile, BK=64, m97-style
// 4 waves (2x2), per-wave 64x64 out (acc[4][4]). Single-buffered 32 KiB LDS,
// full vmcnt(0) drain per k-tile; 3 wgs/CU (launch_bounds 256,3) so the drain
// hides under the other wgs' MFMA (m97/m114 cross-wg overlap, 874-912 TF).
// Used for S-gemm (TRI=1: packed causal triangle, z=blockIdx.y) and PV
// (TRI=0: br,bc,z direct; kt = base + per_br*br causal truncation).
template <int TRI>
__global__ __launch_bounds__(256, 3) void gemm4(
    const __bf16* __restrict__ A0, int lda, long long sAz,
    const __bf16* __restrict__ B0, int ldb, long long sBz,
    __bf16* __restrict__ C0, int ldc, long long sCz,
    int k_tiles_base, int k_tiles_per_br) {
  int br, bc, z;
  if (TRI) {
    const int c = blockIdx.x;  // 0..135 -> (br,bc), bc<=br, 16 rows
    z = blockIdx.y;
    int b0 = (int)((sqrtf((float)(8 * c + 1)) - 1.0f) * 0.5f);
    int c0 = c - ((b0 * (b0 + 1)) >> 1);
    if (c0 < 0) { b0--; c0 = c - ((b0 * (b0 + 1)) >> 1); }
    if (c0 > b0) { b0++; c0 = c - ((b0 * (b0 + 1)) >> 1); }
    br = b0;
    bc = c0;
  } else {
    br = blockIdx.x;
    bc = blockIdx.y;
    z = blockIdx.z;
  }
  const int kt = k_tiles_base + k_tiles_per_br * br;

  __shared__ __align__(16) __bf16 lds[16384];  // A 8192 elems, B 8192 elems

  const int t = threadIdx.x, w = t >> 6, lane = t & 63;
  const int wm = w >> 1, wn = w & 1;
  const int ln15 = lane & 15, kq = lane >> 4;

  const __bf16* A = A0 + (long long)z * sAz + (long long)br * 128 * lda;
  const __bf16* B = B0 + (long long)z * sBz + (long long)bc * 128 * ldb;

  // staging source coords: linear dest byte o = i*4096 + t*16, inverse-swizzled
  const __bf16 *sA[4], *sB[4];
#pragma unroll
  for (int i = 0; i < 4; i++) {
    int o = i * 4096 + t * 16;
    int lo = o ^ (((o >> 7) & 7) << 4);
    int r = lo >> 7, c = (lo & 127) >> 1;
    sA[i] = A + (long long)r * lda + c;
    sB[i] = B + (long long)r * ldb + c;
  }

  f32x4 acc[4][4] = {};

  for (int kk = 0; kk < kt; kk++) {
    // stage tile kk (wave-uniform LDS dest base + lane x 16B, linear)
#pragma unroll
    for (int i = 0; i < 4; i++)
      gload16(sA[i] + kk * 64, lds + i * 2048 + w * 512);
#pragma unroll
    for (int i = 0; i < 4; i++)
      gload16(sB[i] + kk * 64, lds + 8192 + i * 2048 + w * 512);
    asm volatile("s_waitcnt vmcnt(0)" ::: "memory");
    __builtin_amdgcn_s_barrier();
    FENCE;
    const char* Ab = (const char*)lds;
    const char* Bb = (const char*)(lds + 8192);
    __builtin_amdgcn_s_setprio(1);
#pragma unroll
    for (int kh = 0; kh < 2; kh++) {
      bf16x8 a[4], b[4];
#pragma unroll
      for (int mi = 0; mi < 4; mi++) {
        int row = wm * 64 + mi * 16 + ln15;
        int pb = (row * 128 + (kh * 32 + kq * 8) * 2) ^ ((row & 7) << 4);
        a[mi] = *(const bf16x8*)(Ab + pb);
      }
#pragma unroll
      for (int ni = 0; ni < 4; ni++) {
        int row = wn * 64 + ni * 16 + ln15;
        int pb = (row * 128 + (kh * 32 + kq * 8) * 2) ^ ((row & 7) << 4);
        b[ni] = *(const bf16x8*)(Bb + pb);
      }
#pragma unroll
      for (int mi = 0; mi < 4; mi++)
#pragma unroll
        for (int ni = 0; ni < 4; ni++)
          acc[mi][ni] = __builtin_amdgcn_mfma_f32_16x16x32_bf16(
              a[mi], b[ni], acc[mi][ni], 0, 0, 0);
    }
    __builtin_amdgcn_s_setprio(0);
    FENCE;
    __builtin_amdgcn_s_barrier();  // all reads done before next tile's stage
    FENCE;
  }

  const int row0 = br * 128 + wm * 64 + kq * 4;
  const int col0 = bc * 128 + wn * 64 + ln15;
#pragma unroll
  for (int mi = 0; mi < 4; mi++) {
#pragma unroll
    for (int ni = 0; ni < 4; ni++) {
      const int rr = row0 + mi * 16, cc = col0 + ni * 16;
#pragma unroll
      for (int j = 0; j < 4; j++)
        C0[(long long)z * sCz + (long long)(rr + j) * ldc + cc] =
            (__bf16)acc[mi][ni][j];
    }
  }
}

// ---------------------------------------------------------------- softmax (causal, in-place on S bf16)
__global__ __launch_bounds__(256) void softmax_rows(__bf16* __restrict__ S) {
  const int row = blockIdx.x;  // 0..16383 = b*2048 + i
  const int i = row & 2047;
  __bf16* s = S + (long long)row * 2048;
  const int Lpad = (i + 256) & ~255;  // round_up(i+1, 256): PV reads <= round128(i+1)
  const int t = threadIdx.x;
  const int j0 = t * 8;
  const int wid = t >> 6, lane = t & 63;
  const bool active = j0 < Lpad;

  float v[8];
  float mymax = -3.0e38f;
  if (active) {
    bf16x8 x = *(const bf16x8*)(s + j0);
#pragma unroll
    for (int e = 0; e < 8; e++) {
      float f = (float)x[e];
      v[e] = ((j0 + e) <= i) ? f : -3.0e38f;
      mymax = fmaxf(mymax, v[e]);
    }
  }
  float mw = mymax;
#pragma unroll
  for (int o = 32; o >= 1; o >>= 1) mw = fmaxf(mw, __shfl_xor(mw, o));
  __shared__ float redm[4];
  __shared__ float reds[4];
  if (lane == 0) redm[wid] = mw;
  __syncthreads();
  const float m = fmaxf(fmaxf(redm[0], redm[1]), fmaxf(redm[2], redm[3]));

  float e8[8];
  float mysum = 0.0f;
  if (active) {
#pragma unroll
    for (int e = 0; e < 8; e++) {
      float ev = ((j0 + e) <= i) ? __expf(v[e] - m) : 0.0f;
      e8[e] = ev;
      mysum += ev;
    }
  } else {
#pragma unroll
    for (int e = 0; e < 8; e++) e8[e] = 0.0f;
  }
  float sw = mysum;
#pragma unroll
  for (int o = 32; o >= 1; o >>= 1) sw += __shfl_xor(sw, o);
  if (lane == 0) reds[wid] = sw;
  __syncthreads();
  const float l = reds[0] + reds[1] + reds[2] + reds[3];
  const float rl = 1.0f / l;
  if (active) {
    bf16x8 o;
#pragma unroll
    for (int e = 0; e < 8; e++) o[e] = (__bf16)(e8[e] * rl);
    *(bf16x8*)(s + j0) = o;
  }
}

// ---------------------------------------------------------------- launch
extern "C" void kernel_launch(void* const* d_in, const int* in_sizes, int n_in,
                              void* d_out, int out_size, void* d_ws, size_t ws_size,
                              hipStream_t stream) {
  const float* y  = (const float*)d_in[0];
  const float* Wq = (const float*)d_in[1];
  const float* bq = (const float*)d_in[2];
  const float* Wk = (const float*)d_in[3];
  const float* bk = (const float*)d_in[4];
  const float* Wv = (const float*)d_in[5];
  const float* bv = (const float*)d_in[6];
  const float* Wo = (const float*)d_in[7];
  const float* bo = (const float*)d_in[8];

  char* ws = (char*)d_ws;
  __bf16* Xb   = (__bf16*)(ws + 0);            // 16384x1024 bf16 X   (32 MiB) [ctx after PV]
  __bf16* Wt   = (__bf16*)(ws + 33554432);     // 4 x [1024][1024] bf16 W^T (8 MiB)
  float*  bqkv = (float*)(ws + 41943040);      // 3x1024 fp32
  __bf16* Qb   = (__bf16*)(ws + 41955328);     // 8x2048x1024 Q       (32 MiB)
  __bf16* Kb   = (__bf16*)(ws + 75509760);     // 8x2048x1024 K       (32 MiB)
  __bf16* Vt   = (__bf16*)(ws + 109064192);    // 8 x [1024][2048] V^T (32 MiB)
  __bf16* Sb   = (__bf16*)(ws + 142618624);    // 8x2048x2048 S/P (ends at 209,727,488)
  __bf16* ctx  = (__bf16*)(ws + 0);            // PV output reuses Xb region

  if (ws_size < 209727488u) return;

  convert_bf16_k<<<2048, 256, 0, stream>>>(y, Xb, 2097152);
  pack_bias_k<<<12, 256, 0, stream>>>(bq, bk, bv, bqkv);
  transpose_w_k<<<dim3(32, 32, 4), dim3(32, 8), 0, stream>>>(Wq, Wk, Wv, Wo, Wt);

  // Fused QKV projection (round-4 best config): z-split (z0->Qb scaled,
  // z1->Kb, z2->Vt via LDS transpose), A-stripe swizzle z-slowest.
  gemm8<2, 1><<<dim3(64, 4, 3), 512, 0, stream>>>(
      Xb, 1024, 0LL, Wt, 1024, 1048576LL,
      Qb, 1024, 16777216LL, bqkv, 1024, 0.03125f, 16, 0, Vt);

  // S = Q @ K^T per batch: 128-tile packed causal triangle, 136 x 8 = 1088 wgs
  // (4.25 balanced rounds at 3 wgs/CU).
  gemm4<1><<<dim3(136, 8, 1), 256, 0, stream>>>(
      Qb, 1024, 2097152LL, Kb, 1024, 2097152LL,
      Sb, 2048, 4194304LL, 16, 0);

  // causal softmax in place (zero-pads to 256-block edge)
  softmax_rows<<<16384, 256, 0, stream>>>(Sb);

  // ctx = P @ V : 128-tile, kt = 2*(br+1) causal truncation; 1024 wgs balanced.
  gemm4<0><<<dim3(16, 8, 8), 256, 0, stream>>>(
      Sb, 2048, 4194304LL, Vt, 2048, 2097152LL,
      ctx, 1024, 2097152LL, 2, 2);

  // out = ctx @ Wo + bo (fp32 epilogue to d_out), A-stripe swizzle
  gemm8<1, 1><<<dim3(64, 4, 1), 512, 0, stream>>>(
      ctx, 1024, 0LL, Wt + 3 * 1048576, 1024, 0LL,
      d_out, 1024, 0LL, bo, 0, 1.0f, 16, 0, nullptr);
}

// Round 7
// 332.688 us; speedup vs baseline: 1.0296x; 1.0296x over previous
//
#include <hip/hip_runtime.h>

typedef __attribute__((ext_vector_type(8))) __bf16 bf16x8;
typedef __attribute__((ext_vector_type(4))) float f32x4;
typedef __attribute__((ext_vector_type(4))) float f4;
typedef __attribute__((ext_vector_type(4))) unsigned short ushort4_t;

__device__ inline void gload16(const void* g, void* l) {
  __builtin_amdgcn_global_load_lds(
      (const __attribute__((address_space(1))) unsigned int*)g,
      (__attribute__((address_space(3))) unsigned int*)l, 16, 0, 0);
}

// ---------------------------------------------------------------- converts
__global__ void convert_bf16_k(const float* __restrict__ in, __bf16* __restrict__ out, int n8) {
  int i = blockIdx.x * blockDim.x + threadIdx.x;
  int stride = gridDim.x * blockDim.x;
  for (; i < n8; i += stride) {
    f4 a = ((const f4*)in)[2 * (long long)i];
    f4 b = ((const f4*)in)[2 * (long long)i + 1];
    bf16x8 o;
#pragma unroll
    for (int e = 0; e < 4; e++) { o[e] = (__bf16)a[e]; o[e + 4] = (__bf16)b[e]; }
    ((bf16x8*)out)[i] = o;
  }
}

__global__ void pack_bias_k(const float* __restrict__ bq, const float* __restrict__ bk,
                            const float* __restrict__ bv, float* __restrict__ out) {
  int i = blockIdx.x * 256 + threadIdx.x;
  if (i >= 3072) return;
  const float* src = (i < 1024) ? bq : (i < 2048) ? bk : bv;
  out[i] = src[i & 1023];
}

// W[k][n] fp32 -> Wt[n][k] bf16, 4 weights via z
__global__ void transpose_w_k(const float* __restrict__ W0, const float* __restrict__ W1,
                              const float* __restrict__ W2, const float* __restrict__ W3,
                              __bf16* __restrict__ out) {
  int z = blockIdx.z;
  const float* W = (z == 0) ? W0 : (z == 1) ? W1 : (z == 2) ? W2 : W3;
  __bf16* O = out + (long long)z * 1048576;
  __shared__ float tile[32][33];
  int tx = threadIdx.x, ty = threadIdx.y;
  int n0 = blockIdx.x * 32, k0 = blockIdx.y * 32;
#pragma unroll
  for (int i = 0; i < 4; i++)
    tile[ty + i * 8][tx] = W[(long long)(k0 + ty + i * 8) * 1024 + n0 + tx];
  __syncthreads();
#pragma unroll
  for (int i = 0; i < 4; i++)
    O[(long long)(n0 + ty + i * 8) * 1024 + k0 + tx] = (__bf16)tile[tx][ty + i * 8];
}

#define FENCE asm volatile("" ::: "memory")

// ---------------------------------------------------------------- gemm8: 256x256 tile, BK=64, 8-phase
// (round-4 form). Used for S-gemm (SWZ=2 causal triangle) and PV (SWZ=3).
// LDS 160 KiB: A triple-buffered + B double-buffered, XOR-swizzled (row&7)<<4.
// A(kk+2) issued during tile kk; B(kk+2) overwrites-behind. ENDPB vmcnt(8).

#define LOADA(BASE, MIB)                                                       \
  _Pragma("unroll") for (int mi = 0; mi < 4; mi++)                             \
      _Pragma("unroll") for (int kh = 0; kh < 2; kh++) {                       \
    int row = ((MIB) + mi) * 16 + ln15;                                        \
    int pb = (row * 128 + (kh * 32 + kq * 8) * 2) ^ ((row & 7) << 4);          \
    a[mi][kh] = *(const bf16x8*)((BASE) + pb);                                 \
  }

#define LOADB(BASE, NIB)                                                       \
  _Pragma("unroll") for (int ni = 0; ni < 2; ni++)                             \
      _Pragma("unroll") for (int kh = 0; kh < 2; kh++) {                       \
    int row = brow0 + ((NIB) + ni) * 16 + ln15;                                \
    int pb = (row * 128 + (kh * 32 + kq * 8) * 2) ^ ((row & 7) << 4);          \
    b[(NIB) + ni][kh] = *(const bf16x8*)((BASE) + pb);                         \
  }

#define MFMAQ(MI0, NI0)                                                        \
  _Pragma("unroll") for (int mi = 0; mi < 4; mi++)                             \
      _Pragma("unroll") for (int ni = 0; ni < 2; ni++)                         \
          _Pragma("unroll") for (int kh = 0; kh < 2; kh++)                     \
              acc[(MI0) + mi][(NI0) + ni] =                                    \
      __builtin_amdgcn_mfma_f32_16x16x32_bf16(a[mi][kh], b[(NI0) + ni][kh],    \
                                              acc[(MI0) + mi][(NI0) + ni], 0, 0, 0);

#define BARW                                           \
  FENCE;                                               \
  __builtin_amdgcn_s_barrier();                        \
  FENCE;                                               \
  __builtin_amdgcn_s_setprio(1);

#define ENDP                                           \
  __builtin_amdgcn_s_setprio(0);                       \
  FENCE;                                               \
  __builtin_amdgcn_s_barrier();                        \
  FENCE;

#define ENDPB                                          \
  __builtin_amdgcn_s_setprio(0);                       \
  asm volatile("s_waitcnt vmcnt(8)" ::: "memory");     \
  __builtin_amdgcn_s_barrier();                        \
  FENCE;

template <int OUT, int SWZ>
__global__ __launch_bounds__(512, 2) void gemm8(
    const __bf16* __restrict__ A0, int lda, long long sAz,
    const __bf16* __restrict__ B0, int ldb, long long sBz,
    void* __restrict__ C0v, int ldc, long long sCz,
    const float* __restrict__ bias0, int sBiasZ,
    float scale_z0, int k_tiles_base, int k_tiles_per_br,
    __bf16* __restrict__ vt_out) {
  int br, bc, z;
  {
    const int lin = (blockIdx.z * gridDim.y + blockIdx.y) * gridDim.x + blockIdx.x;
    if (SWZ == 2) {
      // packed lower triangle, one batch per XCD; c in [0,36) -> (br,bc) bc<=br
      const int q = lin & 7, c = lin >> 3;
      z = q;
      int b0 = (int)((sqrtf((float)(8 * c + 1)) - 1.0f) * 0.5f);
      int c0 = c - ((b0 * (b0 + 1)) >> 1);
      if (c0 < 0) { b0--; c0 = c - ((b0 * (b0 + 1)) >> 1); }
      if (c0 > b0) { b0++; c0 = c - ((b0 * (b0 + 1)) >> 1); }
      br = b0;
      bc = c0;
    } else if (SWZ == 3) {
      // batch-local: XCD q = batch q; c -> (br fast, bc)
      const int q = lin & 7, c = lin >> 3;
      z = q;
      br = c & 7;
      bc = c >> 3;
    } else {
      const int nbx = gridDim.x, nby = gridDim.y;
      const int nwg = nbx * nby * gridDim.z;
      const int cpx = nwg >> 3;
      const int swz = (lin & 7) * cpx + (lin >> 3);
      br = swz % nbx;
      const int tmp = swz / nbx;
      bc = tmp % nby;
      z = tmp / nby;
    }
  }
  const int kt = k_tiles_base + k_tiles_per_br * br;  // >= 2

  // 160 KiB LDS: A bufs at 0,16384,32768 (elems); B bufs at 49152,65536
  __shared__ __align__(16) __bf16 lds[81920];

  const int t = threadIdx.x, w = t >> 6, lane = t & 63;
  const int wm = w >> 2, wn = w & 3;
  const int ln15 = lane & 15, kq = lane >> 4;
  const int bh = wn >> 1, brow0 = (wn & 1) * 64;

  const __bf16* A = A0 + (long long)z * sAz + (long long)br * 256 * lda;
  const __bf16* B = B0 + (long long)z * sBz + (long long)bc * 256 * ldb;

  int r0s[2], c0s[2];
#pragma unroll
  for (int i = 0; i < 2; i++) {
    int o = i * 8192 + t * 16;
    int lo = o ^ (((o >> 7) & 7) << 4);
    r0s[i] = lo >> 7;
    c0s[i] = (lo & 127) >> 1;
  }
  const __bf16 *sA0[2], *sA1[2], *sB0[2], *sB1[2];
#pragma unroll
  for (int i = 0; i < 2; i++) {
    sA0[i] = A + (long long)r0s[i] * lda + c0s[i];
    sA1[i] = A + (long long)(r0s[i] + 128) * lda + c0s[i];
    sB0[i] = B + (long long)r0s[i] * ldb + c0s[i];
    sB1[i] = B + (long long)(r0s[i] + 128) * ldb + c0s[i];
  }

  auto stg = [&](const __bf16* const* src, __bf16* lbase, int g) {
    int kc = g < kt ? g : kt - 1;  // clamped dup keeps per-iter issue count = 8
#pragma unroll
    for (int i = 0; i < 2; i++)
      gload16(src[i] + kc * 64, lbase + i * 4096 + w * 512);
  };

  f32x4 acc[8][4] = {};
  bf16x8 a[4][2], b[4][2];

  stg(sA0, lds, 0);
  stg(sA1, lds + 8192, 0);
  stg(sB0, lds + 49152, 0);
  stg(sB1, lds + 49152 + 8192, 0);
  stg(sA0, lds + 16384, 1);
  stg(sA1, lds + 16384 + 8192, 1);
  stg(sB0, lds + 65536, 1);
  stg(sB1, lds + 65536 + 8192, 1);
  asm volatile("s_waitcnt vmcnt(8)" ::: "memory");
  __builtin_amdgcn_s_barrier();
  FENCE;

  int ap = 0, ad = 2;
  for (int kk = 0; kk < kt; kk++) {
    __bf16* Ab = lds + ap * 16384;
    __bf16* Bb = lds + 49152 + (kk & 1) * 16384;
    __bf16* Ad = lds + ad * 16384;
    __bf16* Bd = Bb;
    const char* Aw = (const char*)(Ab + wm * 8192);
    const char* Bw = (const char*)(Bb + bh * 8192);
    LOADA(Aw, 0) LOADB(Bw, 0)
    stg(sA0, Ad, kk + 2);
    BARW MFMAQ(0, 0) ENDP
    LOADB(Bw, 2)
    stg(sA1, Ad + 8192, kk + 2);
    BARW MFMAQ(0, 2) ENDP
    LOADA(Aw, 4)
    stg(sB0, Bd, kk + 2);
    BARW MFMAQ(4, 2) ENDP
    stg(sB1, Bd + 8192, kk + 2);
    BARW MFMAQ(4, 0) ENDPB
    ap = (ap == 2) ? 0 : ap + 1;
    ad = (ad == 2) ? 0 : ad + 1;
  }

  {
    const int row0 = br * 256 + wm * 128 + kq * 4;
    const int col0 = bc * 256 + wn * 64 + ln15;
    const float scale = (z == 0) ? scale_z0 : 1.0f;
    const float* bias = bias0 ? (bias0 + (long long)z * sBiasZ) : nullptr;
#pragma unroll
    for (int mi = 0; mi < 8; mi++) {
#pragma unroll
      for (int ni = 0; ni < 4; ni++) {
        const int rr = row0 + mi * 16;
        const int cc = col0 + ni * 16;
        const float bb = bias ? bias[cc] : 0.0f;
#pragma unroll
        for (int j = 0; j < 4; j++) {
          float v = (acc[mi][ni][j] + bb) * scale;
          long long off = (long long)z * sCz + (long long)(rr + j) * ldc + cc;
          if (OUT == 1)
            ((float*)C0v)[off] = v;
          else
            ((__bf16*)C0v)[off] = (__bf16)v;
        }
      }
    }
  }
  (void)vt_out;
}

// ---------------------------------------------------------------- gemm2w: 128x256 tile, BK=32, 2 wgs/CU
// 8 waves (2M x 4N), per-wave 64x64 (acc[4][4] = 64 VGPR -> 4 waves/SIMD).
// LDS 72 KiB: A triple-buffered (3 x 8 KiB) + B triple-buffered (3 x 16 KiB),
// XOR-swizzled ((row&3)<<4). 2-deep prefetch: tile kk issues kk+2's 3 loads;
// ENDPB-equivalent waits vmcnt(3) (FIFO: drains kk+1's 3, leaves kk+2's 3).
// Two wgs co-resident per CU: one wg's barrier/vmcnt stalls are covered by the
// other wg's MFMA issue (m114 co-scheduling) - the lever all 1-wg/CU variants
// lacked. A-stripe swizzle: XCD q owns br in [16q,16q+16), br fastest.
// OUT: 1 = f32 C; 2 = fused QKV z-routing (z<2 scalar bf16 C, z==2 V
//      LDS-transposed into vt_out[b][d][t]).
template <int OUT>
__global__ __launch_bounds__(512, 4) void gemm2w(
    const __bf16* __restrict__ A0, int lda, long long sAz,
    const __bf16* __restrict__ B0, int ldb, long long sBz,
    void* __restrict__ C0v, int ldc, long long sCz,
    const float* __restrict__ bias0, int sBiasZ,
    float scale_z0, int kt, __bf16* __restrict__ vt_out) {
  int br, bc, z;
  {
    const int lin = (blockIdx.z * gridDim.y + blockIdx.y) * gridDim.x + blockIdx.x;
    const int q = lin & 7, c = lin >> 3;
    br = q * 16 + (c & 15);
    const int rest = c >> 4;
    const int nby = gridDim.y;
    bc = rest % nby;
    z = rest / nby;
  }

  // 72 KiB LDS: A bufs at 0,4096,8192 (elems); B bufs at 12288,20480,28672
  __shared__ __align__(16) __bf16 lds[36864];

  const int t = threadIdx.x, w = t >> 6, lane = t & 63;
  const int wm = w >> 2, wn = w & 3;
  const int ln15 = lane & 15, kq = lane >> 4;

  const __bf16* A = A0 + (long long)z * sAz + (long long)br * 128 * lda;
  const __bf16* B = B0 + (long long)z * sBz + (long long)bc * 256 * ldb;

  // staging src (dest linear o = t*16 bytes, inverse-swizzled; row = 64B line)
  const __bf16* sA;
  const __bf16* sB[2];
  {
    int o = t * 16;
    int lo = o ^ (((o >> 6) & 3) << 4);
    sA = A + (long long)(lo >> 6) * lda + ((lo & 63) >> 1);
  }
#pragma unroll
  for (int i = 0; i < 2; i++) {
    int o = i * 8192 + t * 16;
    int lo = o ^ (((o >> 6) & 3) << 4);
    sB[i] = B + (long long)(lo >> 6) * ldb + ((lo & 63) >> 1);
  }

  auto stgA = [&](int buf, int g) {
    int kc = g < kt ? g : kt - 1;
    gload16(sA + kc * 32, lds + buf * 4096 + w * 512);
  };
  auto stgB = [&](int buf, int g) {
    int kc = g < kt ? g : kt - 1;
#pragma unroll
    for (int i = 0; i < 2; i++)
      gload16(sB[i] + kc * 32, lds + 12288 + buf * 8192 + i * 4096 + w * 512);
  };

  f32x4 acc[4][4] = {};
  bf16x8 a[4], b[4];

  // prologue: tiles 0 and 1 (3 loads each); vmcnt(3) -> tile 0 resident
  stgA(0, 0); stgB(0, 0);
  stgA(1, 1); stgB(1, 1);
  asm volatile("s_waitcnt vmcnt(3)" ::: "memory");
  __builtin_amdgcn_s_barrier();
  FENCE;

  int cb = 0, db = 2;
  for (int kk = 0; kk < kt; kk++) {
    const char* Ab = (const char*)(lds + cb * 4096);
    const char* Bb = (const char*)(lds + 12288 + cb * 8192);
#pragma unroll
    for (int mi = 0; mi < 4; mi++) {
      int row = wm * 64 + mi * 16 + ln15;
      int pb = (row * 64 + kq * 16) ^ ((row & 3) << 4);
      a[mi] = *(const bf16x8*)(Ab + pb);
    }
#pragma unroll
    for (int ni = 0; ni < 4; ni++) {
      int row = wn * 64 + ni * 16 + ln15;
      int pb = (row * 64 + kq * 16) ^ ((row & 3) << 4);
      b[ni] = *(const bf16x8*)(Bb + pb);
    }
    stgA(db, kk + 2);
    stgB(db, kk + 2);
    FENCE;
    __builtin_amdgcn_s_barrier();
    FENCE;
    __builtin_amdgcn_s_setprio(1);
#pragma unroll
    for (int mi = 0; mi < 4; mi++)
#pragma unroll
      for (int ni = 0; ni < 4; ni++)
        acc[mi][ni] = __builtin_amdgcn_mfma_f32_16x16x32_bf16(
            a[mi], b[ni], acc[mi][ni], 0, 0, 0);
    __builtin_amdgcn_s_setprio(0);
    asm volatile("s_waitcnt vmcnt(3)" ::: "memory");
    __builtin_amdgcn_s_barrier();
    FENCE;
    cb = (cb == 2) ? 0 : cb + 1;
    db = (db == 2) ? 0 : db + 1;
  }
  // drain clamped-dup prefetches before LDS reuse / exit (stale DMA safety)
  asm volatile("s_waitcnt vmcnt(0)" ::: "memory");

  if (OUT == 2 && z == 2) {
    // V: stage 128(t) x 256(d) tile into LDS as [d][t] (XOR ((d&3)<<4)), then
    // coalesced 16B stores into vt_out[b][d][t].
    __syncthreads();
    char* lb = (char*)lds;
#pragma unroll
    for (int mi = 0; mi < 4; mi++) {
#pragma unroll
      for (int ni = 0; ni < 4; ni++) {
        const int d = wn * 64 + ni * 16 + ln15;
        const int tl = wm * 64 + kq * 4 + mi * 16;
        const float bb = bias0[2048 + bc * 256 + d];
        ushort4_t p;
#pragma unroll
        for (int j = 0; j < 4; j++) {
          union { __bf16 h; unsigned short u; } cv;
          cv.h = (__bf16)(acc[mi][ni][j] + bb);
          p[j] = cv.u;
        }
        int byte = (d * 256 + tl * 2) ^ ((d & 3) << 4);
        *(ushort4_t*)(lb + byte) = p;
      }
    }
    __syncthreads();
    const int bz = br >> 4;
    const int t0 = (br & 15) * 128;
    __bf16* vbase = vt_out + (long long)bz * 2097152 +
                    (long long)(bc * 256) * 2048 + t0;
#pragma unroll
    for (int it = 0; it < 8; it++) {
      int idx = it * 512 + t;  // 16B units, 4096 total (256 d x 16)
      int d = idx >> 4, tc = idx & 15;
      int byte = (d * 256 + tc * 16) ^ ((d & 3) << 4);
      bf16x8 vv = *(const bf16x8*)(lb + byte);
      *(bf16x8*)(vbase + (long long)d * 2048 + tc * 8) = vv;
    }
  } else {
    const int row0 = br * 128 + wm * 64 + kq * 4;
    const int col0 = bc * 256 + wn * 64 + ln15;
    const float scale = (z == 0) ? scale_z0 : 1.0f;
    const float* bias = bias0 ? (bias0 + (long long)z * sBiasZ) : nullptr;
#pragma unroll
    for (int mi = 0; mi < 4; mi++) {
#pragma unroll
      for (int ni = 0; ni < 4; ni++) {
        const int rr = row0 + mi * 16;
        const int cc = col0 + ni * 16;
        const float bb = bias ? bias[cc] : 0.0f;
#pragma unroll
        for (int j = 0; j < 4; j++) {
          float v = (acc[mi][ni][j] + bb) * scale;
          long long off = (long long)z * sCz + (long long)(rr + j) * ldc + cc;
          if (OUT == 1)
            ((float*)C0v)[off] = v;
          else
            ((__bf16*)C0v)[off] = (__bf16)v;
        }
      }
    }
  }
}

// ---------------------------------------------------------------- softmax (causal, in-place on S bf16)
__global__ __launch_bounds__(256) void softmax_rows(__bf16* __restrict__ S) {
  const int row = blockIdx.x;  // 0..16383 = b*2048 + i
  const int i = row & 2047;
  __bf16* s = S + (long long)row * 2048;
  const int Lpad = (i + 256) & ~255;  // round_up(i+1, 256): PV reads this far
  const int t = threadIdx.x;
  const int j0 = t * 8;
  const int wid = t >> 6, lane = t & 63;
  const bool active = j0 < Lpad;

  float v[8];
  float mymax = -3.0e38f;
  if (active) {
    bf16x8 x = *(const bf16x8*)(s + j0);
#pragma unroll
    for (int e = 0; e < 8; e++) {
      float f = (float)x[e];
      v[e] = ((j0 + e) <= i) ? f : -3.0e38f;
      mymax = fmaxf(mymax, v[e]);
    }
  }
  float mw = mymax;
#pragma unroll
  for (int o = 32; o >= 1; o >>= 1) mw = fmaxf(mw, __shfl_xor(mw, o));
  __shared__ float redm[4];
  __shared__ float reds[4];
  if (lane == 0) redm[wid] = mw;
  __syncthreads();
  const float m = fmaxf(fmaxf(redm[0], redm[1]), fmaxf(redm[2], redm[3]));

  float e8[8];
  float mysum = 0.0f;
  if (active) {
#pragma unroll
    for (int e = 0; e < 8; e++) {
      float ev = ((j0 + e) <= i) ? __expf(v[e] - m) : 0.0f;
      e8[e] = ev;
      mysum += ev;
    }
  } else {
#pragma unroll
    for (int e = 0; e < 8; e++) e8[e] = 0.0f;
  }
  float sw = mysum;
#pragma unroll
  for (int o = 32; o >= 1; o >>= 1) sw += __shfl_xor(sw, o);
  if (lane == 0) reds[wid] = sw;
  __syncthreads();
  const float l = reds[0] + reds[1] + reds[2] + reds[3];
  const float rl = 1.0f / l;
  if (active) {
    bf16x8 o;
#pragma unroll
    for (int e = 0; e < 8; e++) o[e] = (__bf16)(e8[e] * rl);
    *(bf16x8*)(s + j0) = o;
  }
}

// ---------------------------------------------------------------- launch
extern "C" void kernel_launch(void* const* d_in, const int* in_sizes, int n_in,
                              void* d_out, int out_size, void* d_ws, size_t ws_size,
                              hipStream_t stream) {
  const float* y  = (const float*)d_in[0];
  const float* Wq = (const float*)d_in[1];
  const float* bq = (const float*)d_in[2];
  const float* Wk = (const float*)d_in[3];
  const float* bk = (const float*)d_in[4];
  const float* Wv = (const float*)d_in[5];
  const float* bv = (const float*)d_in[6];
  const float* Wo = (const float*)d_in[7];
  const float* bo = (const float*)d_in[8];

  char* ws = (char*)d_ws;
  __bf16* Xb   = (__bf16*)(ws + 0);            // 16384x1024 bf16 X   (32 MiB) [ctx after PV]
  __bf16* Wt   = (__bf16*)(ws + 33554432);     // 4 x [1024][1024] bf16 W^T (8 MiB)
  float*  bqkv = (float*)(ws + 41943040);      // 3x1024 fp32
  __bf16* Qb   = (__bf16*)(ws + 41955328);     // 8x2048x1024 Q       (32 MiB)
  __bf16* Kb   = (__bf16*)(ws + 75509760);     // 8x2048x1024 K       (32 MiB)
  __bf16* Vt   = (__bf16*)(ws + 109064192);    // 8 x [1024][2048] V^T (32 MiB)
  __bf16* Sb   = (__bf16*)(ws + 142618624);    // 8x2048x2048 S/P (ends at 209,727,488)
  __bf16* ctx  = (__bf16*)(ws + 0);            // PV output reuses Xb region

  if (ws_size < 209727488u) return;

  convert_bf16_k<<<2048, 256, 0, stream>>>(y, Xb, 2097152);
  pack_bias_k<<<12, 256, 0, stream>>>(bq, bk, bv, bqkv);
  transpose_w_k<<<dim3(32, 32, 4), dim3(32, 8), 0, stream>>>(Wq, Wk, Wv, Wo, Wt);

  // Fused QKV projection: 128x256-tile 2-wg/CU kernel, z-split (z0->Qb scaled,
  // z1->Kb, z2->Vt via LDS transpose). A-stripe swizzle (z slowest).
  gemm2w<2><<<dim3(128, 4, 3), 512, 0, stream>>>(
      Xb, 1024, 0LL, Wt, 1024, 1048576LL,
      Qb, 1024, 16777216LL, bqkv, 1024, 0.03125f, 32, Vt);

  // S = Q @ K^T per batch: packed lower-triangle launch (36 tiles x 8 batches)
  gemm8<0, 2><<<dim3(36, 1, 8), 512, 0, stream>>>(
      Qb, 1024, 2097152LL, Kb, 1024, 2097152LL,
      Sb, 2048, 4194304LL, nullptr, 0, 1.0f, 16, 0, nullptr);

  // causal softmax in place (zero-pads to 256-block edge)
  softmax_rows<<<16384, 256, 0, stream>>>(Sb);

  // ctx = P @ V : kt = 4*(br+1) causal truncation; batch-local swizzle
  gemm8<0, 3><<<dim3(8, 4, 8), 512, 0, stream>>>(
      Sb, 2048, 4194304LL, Vt, 2048, 2097152LL,
      ctx, 1024, 2097152LL, nullptr, 0, 1.0f, 4, 4, nullptr);

  // out = ctx @ Wo + bo (fp32 epilogue to d_out), 2-wg/CU kernel
  gemm2w<1><<<dim3(128, 4, 1), 512, 0, stream>>>(
      ctx, 1024, 0LL, Wt + 3 * 1048576, 1024, 0LL,
      d_out, 1024, 0LL, bo, 0, 1.0f, 32, nullptr);
}

// Round 8
// 329.345 us; speedup vs baseline: 1.0401x; 1.0102x over previous
//
#include <hip/hip_runtime.h>

typedef __attribute__((ext_vector_type(8))) __bf16 bf16x8;
typedef __attribute__((ext_vector_type(4))) float f32x4;
typedef __attribute__((ext_vector_type(4))) float f4;
typedef __attribute__((ext_vector_type(4))) unsigned short ushort4_t;

__device__ inline void gload16(const void* g, void* l) {
  __builtin_amdgcn_global_load_lds(
      (const __attribute__((address_space(1))) unsigned int*)g,
      (__attribute__((address_space(3))) unsigned int*)l, 16, 0, 0);
}

// ---------------------------------------------------------------- converts
__global__ void convert_bf16_k(const float* __restrict__ in, __bf16* __restrict__ out, int n8) {
  int i = blockIdx.x * blockDim.x + threadIdx.x;
  int stride = gridDim.x * blockDim.x;
  for (; i < n8; i += stride) {
    f4 a = ((const f4*)in)[2 * (long long)i];
    f4 b = ((const f4*)in)[2 * (long long)i + 1];
    bf16x8 o;
#pragma unroll
    for (int e = 0; e < 4; e++) { o[e] = (__bf16)a[e]; o[e + 4] = (__bf16)b[e]; }
    ((bf16x8*)out)[i] = o;
  }
}

__global__ void pack_bias_k(const float* __restrict__ bq, const float* __restrict__ bk,
                            const float* __restrict__ bv, float* __restrict__ out) {
  int i = blockIdx.x * 256 + threadIdx.x;
  if (i >= 3072) return;
  const float* src = (i < 1024) ? bq : (i < 2048) ? bk : bv;
  out[i] = src[i & 1023];
}

// W[k][n] fp32 -> Wt[n][k] bf16, 4 weights via z
__global__ void transpose_w_k(const float* __restrict__ W0, const float* __restrict__ W1,
                              const float* __restrict__ W2, const float* __restrict__ W3,
                              __bf16* __restrict__ out) {
  int z = blockIdx.z;
  const float* W = (z == 0) ? W0 : (z == 1) ? W1 : (z == 2) ? W2 : W3;
  __bf16* O = out + (long long)z * 1048576;
  __shared__ float tile[32][33];
  int tx = threadIdx.x, ty = threadIdx.y;
  int n0 = blockIdx.x * 32, k0 = blockIdx.y * 32;
#pragma unroll
  for (int i = 0; i < 4; i++)
    tile[ty + i * 8][tx] = W[(long long)(k0 + ty + i * 8) * 1024 + n0 + tx];
  __syncthreads();
#pragma unroll
  for (int i = 0; i < 4; i++)
    O[(long long)(n0 + ty + i * 8) * 1024 + k0 + tx] = (__bf16)tile[tx][ty + i * 8];
}

#define FENCE asm volatile("" ::: "memory")

// ---------------------------------------------------------------- gemm8: 256x256 tile, BK=64, 8-phase
// (round-4 form). Used for S-gemm (SWZ=2), PV (SWZ=3), out-proj (SWZ=1).
// LDS 160 KiB: A triple-buffered + B double-buffered, XOR-swizzled (row&7)<<4.
// A(kk+2) issued during tile kk; B(kk+2) overwrites-behind. ENDPB vmcnt(8).

#define LOADA(BASE, MIB)                                                       \
  _Pragma("unroll") for (int mi = 0; mi < 4; mi++)                             \
      _Pragma("unroll") for (int kh = 0; kh < 2; kh++) {                       \
    int row = ((MIB) + mi) * 16 + ln15;                                        \
    int pb = (row * 128 + (kh * 32 + kq * 8) * 2) ^ ((row & 7) << 4);          \
    a[mi][kh] = *(const bf16x8*)((BASE) + pb);                                 \
  }

#define LOADB(BASE, NIB)                                                       \
  _Pragma("unroll") for (int ni = 0; ni < 2; ni++)                             \
      _Pragma("unroll") for (int kh = 0; kh < 2; kh++) {                       \
    int row = brow0 + ((NIB) + ni) * 16 + ln15;                                \
    int pb = (row * 128 + (kh * 32 + kq * 8) * 2) ^ ((row & 7) << 4);          \
    b[(NIB) + ni][kh] = *(const bf16x8*)((BASE) + pb);                         \
  }

#define MFMAQ(MI0, NI0)                                                        \
  _Pragma("unroll") for (int mi = 0; mi < 4; mi++)                             \
      _Pragma("unroll") for (int ni = 0; ni < 2; ni++)                         \
          _Pragma("unroll") for (int kh = 0; kh < 2; kh++)                     \
              acc[(MI0) + mi][(NI0) + ni] =                                    \
      __builtin_amdgcn_mfma_f32_16x16x32_bf16(a[mi][kh], b[(NI0) + ni][kh],    \
                                              acc[(MI0) + mi][(NI0) + ni], 0, 0, 0);

#define BARW                                           \
  FENCE;                                               \
  __builtin_amdgcn_s_barrier();                        \
  FENCE;                                               \
  __builtin_amdgcn_s_setprio(1);

#define ENDP                                           \
  __builtin_amdgcn_s_setprio(0);                       \
  FENCE;                                               \
  __builtin_amdgcn_s_barrier();                        \
  FENCE;

#define ENDPB                                          \
  __builtin_amdgcn_s_setprio(0);                       \
  asm volatile("s_waitcnt vmcnt(8)" ::: "memory");     \
  __builtin_amdgcn_s_barrier();                        \
  FENCE;

template <int OUT, int SWZ>
__global__ __launch_bounds__(512, 2) void gemm8(
    const __bf16* __restrict__ A0, int lda, long long sAz,
    const __bf16* __restrict__ B0, int ldb, long long sBz,
    void* __restrict__ C0v, int ldc, long long sCz,
    const float* __restrict__ bias0, int sBiasZ,
    float scale_z0, int k_tiles_base, int k_tiles_per_br,
    __bf16* __restrict__ vt_out) {
  int br, bc, z;
  {
    const int lin = (blockIdx.z * gridDim.y + blockIdx.y) * gridDim.x + blockIdx.x;
    if (SWZ == 1) {
      // A-stripe: XCD q -> br in [8q,8q+8), br fastest; then bc; then z.
      const int q = lin & 7, c = lin >> 3;
      br = q * 8 + (c & 7);
      const int rest = c >> 3;
      const int nby = gridDim.y;
      bc = rest % nby;
      z = rest / nby;
    } else if (SWZ == 2) {
      // packed lower triangle, one batch per XCD; c in [0,36) -> (br,bc) bc<=br
      const int q = lin & 7, c = lin >> 3;
      z = q;
      int b0 = (int)((sqrtf((float)(8 * c + 1)) - 1.0f) * 0.5f);
      int c0 = c - ((b0 * (b0 + 1)) >> 1);
      if (c0 < 0) { b0--; c0 = c - ((b0 * (b0 + 1)) >> 1); }
      if (c0 > b0) { b0++; c0 = c - ((b0 * (b0 + 1)) >> 1); }
      br = b0;
      bc = c0;
    } else if (SWZ == 3) {
      // batch-local: XCD q = batch q; c -> (br fast, bc)
      const int q = lin & 7, c = lin >> 3;
      z = q;
      br = c & 7;
      bc = c >> 3;
    } else {
      const int nbx = gridDim.x, nby = gridDim.y;
      const int nwg = nbx * nby * gridDim.z;
      const int cpx = nwg >> 3;
      const int swz = (lin & 7) * cpx + (lin >> 3);
      br = swz % nbx;
      const int tmp = swz / nbx;
      bc = tmp % nby;
      z = tmp / nby;
    }
  }
  const int kt = k_tiles_base + k_tiles_per_br * br;  // >= 2

  // 160 KiB LDS: A bufs at 0,16384,32768 (elems); B bufs at 49152,65536
  __shared__ __align__(16) __bf16 lds[81920];

  const int t = threadIdx.x, w = t >> 6, lane = t & 63;
  const int wm = w >> 2, wn = w & 3;
  const int ln15 = lane & 15, kq = lane >> 4;
  const int bh = wn >> 1, brow0 = (wn & 1) * 64;

  const __bf16* A = A0 + (long long)z * sAz + (long long)br * 256 * lda;
  const __bf16* B = B0 + (long long)z * sBz + (long long)bc * 256 * ldb;

  int r0s[2], c0s[2];
#pragma unroll
  for (int i = 0; i < 2; i++) {
    int o = i * 8192 + t * 16;
    int lo = o ^ (((o >> 7) & 7) << 4);
    r0s[i] = lo >> 7;
    c0s[i] = (lo & 127) >> 1;
  }
  const __bf16 *sA0[2], *sA1[2], *sB0[2], *sB1[2];
#pragma unroll
  for (int i = 0; i < 2; i++) {
    sA0[i] = A + (long long)r0s[i] * lda + c0s[i];
    sA1[i] = A + (long long)(r0s[i] + 128) * lda + c0s[i];
    sB0[i] = B + (long long)r0s[i] * ldb + c0s[i];
    sB1[i] = B + (long long)(r0s[i] + 128) * ldb + c0s[i];
  }

  auto stg = [&](const __bf16* const* src, __bf16* lbase, int g) {
    int kc = g < kt ? g : kt - 1;  // clamped dup keeps per-iter issue count = 8
#pragma unroll
    for (int i = 0; i < 2; i++)
      gload16(src[i] + kc * 64, lbase + i * 4096 + w * 512);
  };

  f32x4 acc[8][4] = {};
  bf16x8 a[4][2], b[4][2];

  stg(sA0, lds, 0);
  stg(sA1, lds + 8192, 0);
  stg(sB0, lds + 49152, 0);
  stg(sB1, lds + 49152 + 8192, 0);
  stg(sA0, lds + 16384, 1);
  stg(sA1, lds + 16384 + 8192, 1);
  stg(sB0, lds + 65536, 1);
  stg(sB1, lds + 65536 + 8192, 1);
  asm volatile("s_waitcnt vmcnt(8)" ::: "memory");
  __builtin_amdgcn_s_barrier();
  FENCE;

  int ap = 0, ad = 2;
  for (int kk = 0; kk < kt; kk++) {
    __bf16* Ab = lds + ap * 16384;
    __bf16* Bb = lds + 49152 + (kk & 1) * 16384;
    __bf16* Ad = lds + ad * 16384;
    __bf16* Bd = Bb;
    const char* Aw = (const char*)(Ab + wm * 8192);
    const char* Bw = (const char*)(Bb + bh * 8192);
    LOADA(Aw, 0) LOADB(Bw, 0)
    stg(sA0, Ad, kk + 2);
    BARW MFMAQ(0, 0) ENDP
    LOADB(Bw, 2)
    stg(sA1, Ad + 8192, kk + 2);
    BARW MFMAQ(0, 2) ENDP
    LOADA(Aw, 4)
    stg(sB0, Bd, kk + 2);
    BARW MFMAQ(4, 2) ENDP
    stg(sB1, Bd + 8192, kk + 2);
    BARW MFMAQ(4, 0) ENDPB
    ap = (ap == 2) ? 0 : ap + 1;
    ad = (ad == 2) ? 0 : ad + 1;
  }

  {
    const int row0 = br * 256 + wm * 128 + kq * 4;
    const int col0 = bc * 256 + wn * 64 + ln15;
    const float scale = (z == 0) ? scale_z0 : 1.0f;
    const float* bias = bias0 ? (bias0 + (long long)z * sBiasZ) : nullptr;
#pragma unroll
    for (int mi = 0; mi < 8; mi++) {
#pragma unroll
      for (int ni = 0; ni < 4; ni++) {
        const int rr = row0 + mi * 16;
        const int cc = col0 + ni * 16;
        const float bb = bias ? bias[cc] : 0.0f;
#pragma unroll
        for (int j = 0; j < 4; j++) {
          float v = (acc[mi][ni][j] + bb) * scale;
          long long off = (long long)z * sCz + (long long)(rr + j) * ldc + cc;
          if (OUT == 1)
            ((float*)C0v)[off] = v;
          else
            ((__bf16*)C0v)[off] = (__bf16)v;
        }
      }
    }
  }
  (void)vt_out;
}

// ---------------------------------------------------------------- gemm2w: 128x256 tile, BK=32, 2 wgs/CU
// 8 waves (2M x 4N), per-wave 64x64 (acc[4][4] = 64 VGPR -> 4 waves/SIMD).
// LDS 72 KiB: A triple-buffered (3 x 8 KiB) + B triple-buffered (3 x 16 KiB).
// Swizzle ^(((row>>1)&3)<<4): bank-group = (row&1)<<2 | (kq ^ ((row>>1)&3)) ->
// 16 rows hit all 8 groups 2x = free 2-way (the (row&3)<<4 variant was 4-way,
// 13.4M conflict cycles in round 7). Involution: touches byte bits 4-5 only
// (within the 64B row). 2-deep prefetch, vmcnt(3) at tile end. 2 wgs/CU ->
// one wg's barrier/vmcnt stalls covered by the other wg's MFMA (m114).
// A-stripe swizzle: XCD q owns br in [16q,16q+16), br fastest.
// OUT: 1 = f32 C; 2 = fused QKV z-routing (z<2 scalar bf16 C, z==2 V
//      LDS-transposed into vt_out[b][d][t]).
template <int OUT>
__global__ __launch_bounds__(512, 4) void gemm2w(
    const __bf16* __restrict__ A0, int lda, long long sAz,
    const __bf16* __restrict__ B0, int ldb, long long sBz,
    void* __restrict__ C0v, int ldc, long long sCz,
    const float* __restrict__ bias0, int sBiasZ,
    float scale_z0, int kt, __bf16* __restrict__ vt_out) {
  int br, bc, z;
  {
    const int lin = (blockIdx.z * gridDim.y + blockIdx.y) * gridDim.x + blockIdx.x;
    const int q = lin & 7, c = lin >> 3;
    br = q * 16 + (c & 15);
    const int rest = c >> 4;
    const int nby = gridDim.y;
    bc = rest % nby;
    z = rest / nby;
  }

  // 72 KiB LDS: A bufs at 0,4096,8192 (elems); B bufs at 12288,20480,28672
  __shared__ __align__(16) __bf16 lds[36864];

  const int t = threadIdx.x, w = t >> 6, lane = t & 63;
  const int wm = w >> 2, wn = w & 3;
  const int ln15 = lane & 15, kq = lane >> 4;

  const __bf16* A = A0 + (long long)z * sAz + (long long)br * 128 * lda;
  const __bf16* B = B0 + (long long)z * sBz + (long long)bc * 256 * ldb;

  // staging src (dest linear o = t*16 bytes, inverse-swizzled; 64B rows;
  // swz touches bits 4-5, row = o>>6 unchanged -> lo = o ^ (((o>>7)&3)<<4))
  const __bf16* sA;
  const __bf16* sB[2];
  {
    int o = t * 16;
    int lo = o ^ (((o >> 7) & 3) << 4);
    sA = A + (long long)(lo >> 6) * lda + ((lo & 63) >> 1);
  }
#pragma unroll
  for (int i = 0; i < 2; i++) {
    int o = i * 8192 + t * 16;
    int lo = o ^ (((o >> 7) & 3) << 4);
    sB[i] = B + (long long)(lo >> 6) * ldb + ((lo & 63) >> 1);
  }

  auto stgA = [&](int buf, int g) {
    int kc = g < kt ? g : kt - 1;
    gload16(sA + kc * 32, lds + buf * 4096 + w * 512);
  };
  auto stgB = [&](int buf, int g) {
    int kc = g < kt ? g : kt - 1;
#pragma unroll
    for (int i = 0; i < 2; i++)
      gload16(sB[i] + kc * 32, lds + 12288 + buf * 8192 + i * 4096 + w * 512);
  };

  f32x4 acc[4][4] = {};
  bf16x8 a[4], b[4];

  // prologue: tiles 0 and 1 (3 loads each); vmcnt(3) -> tile 0 resident
  stgA(0, 0); stgB(0, 0);
  stgA(1, 1); stgB(1, 1);
  asm volatile("s_waitcnt vmcnt(3)" ::: "memory");
  __builtin_amdgcn_s_barrier();
  FENCE;

  int cb = 0, db = 2;
  for (int kk = 0; kk < kt; kk++) {
    const char* Ab = (const char*)(lds + cb * 4096);
    const char* Bb = (const char*)(lds + 12288 + cb * 8192);
#pragma unroll
    for (int mi = 0; mi < 4; mi++) {
      int row = wm * 64 + mi * 16 + ln15;
      int pb = (row * 64 + kq * 16) ^ (((row >> 1) & 3) << 4);
      a[mi] = *(const bf16x8*)(Ab + pb);
    }
#pragma unroll
    for (int ni = 0; ni < 4; ni++) {
      int row = wn * 64 + ni * 16 + ln15;
      int pb = (row * 64 + kq * 16) ^ (((row >> 1) & 3) << 4);
      b[ni] = *(const bf16x8*)(Bb + pb);
    }
    stgA(db, kk + 2);
    stgB(db, kk + 2);
    FENCE;
    __builtin_amdgcn_s_barrier();
    FENCE;
    __builtin_amdgcn_s_setprio(1);
#pragma unroll
    for (int mi = 0; mi < 4; mi++)
#pragma unroll
      for (int ni = 0; ni < 4; ni++)
        acc[mi][ni] = __builtin_amdgcn_mfma_f32_16x16x32_bf16(
            a[mi], b[ni], acc[mi][ni], 0, 0, 0);
    __builtin_amdgcn_s_setprio(0);
    asm volatile("s_waitcnt vmcnt(3)" ::: "memory");
    __builtin_amdgcn_s_barrier();
    FENCE;
    cb = (cb == 2) ? 0 : cb + 1;
    db = (db == 2) ? 0 : db + 1;
  }
  // drain clamped-dup prefetches before LDS reuse / exit (stale DMA safety)
  asm volatile("s_waitcnt vmcnt(0)" ::: "memory");

  if (OUT == 2 && z == 2) {
    // V: stage 128(t) x 256(d) tile into LDS as [d][t] (256B rows, XOR
    // ((d&7)<<4) -> 16 consecutive-d lanes spread over 8 groups = 2-way),
    // then coalesced 16B stores into vt_out[b][d][t].
    __syncthreads();
    char* lb = (char*)lds;
#pragma unroll
    for (int mi = 0; mi < 4; mi++) {
#pragma unroll
      for (int ni = 0; ni < 4; ni++) {
        const int d = wn * 64 + ni * 16 + ln15;
        const int tl = wm * 64 + kq * 4 + mi * 16;
        const float bb = bias0[2048 + bc * 256 + d];
        ushort4_t p;
#pragma unroll
        for (int j = 0; j < 4; j++) {
          union { __bf16 h; unsigned short u; } cv;
          cv.h = (__bf16)(acc[mi][ni][j] + bb);
          p[j] = cv.u;
        }
        int byte = (d * 256 + tl * 2) ^ ((d & 7) << 4);
        *(ushort4_t*)(lb + byte) = p;
      }
    }
    __syncthreads();
    const int bz = br >> 4;
    const int t0 = (br & 15) * 128;
    __bf16* vbase = vt_out + (long long)bz * 2097152 +
                    (long long)(bc * 256) * 2048 + t0;
#pragma unroll
    for (int it = 0; it < 8; it++) {
      int idx = it * 512 + t;  // 16B units, 4096 total (256 d x 16)
      int d = idx >> 4, tc = idx & 15;
      int byte = (d * 256 + tc * 16) ^ ((d & 7) << 4);
      bf16x8 vv = *(const bf16x8*)(lb + byte);
      *(bf16x8*)(vbase + (long long)d * 2048 + tc * 8) = vv;
    }
  } else {
    const int row0 = br * 128 + wm * 64 + kq * 4;
    const int col0 = bc * 256 + wn * 64 + ln15;
    const float scale = (z == 0) ? scale_z0 : 1.0f;
    const float* bias = bias0 ? (bias0 + (long long)z * sBiasZ) : nullptr;
#pragma unroll
    for (int mi = 0; mi < 4; mi++) {
#pragma unroll
      for (int ni = 0; ni < 4; ni++) {
        const int rr = row0 + mi * 16;
        const int cc = col0 + ni * 16;
        const float bb = bias ? bias[cc] : 0.0f;
#pragma unroll
        for (int j = 0; j < 4; j++) {
          float v = (acc[mi][ni][j] + bb) * scale;
          long long off = (long long)z * sCz + (long long)(rr + j) * ldc + cc;
          if (OUT == 1)
            ((float*)C0v)[off] = v;
          else
            ((__bf16*)C0v)[off] = (__bf16)v;
        }
      }
    }
  }
}

// ---------------------------------------------------------------- softmax (causal, in-place on S bf16)
__global__ __launch_bounds__(256) void softmax_rows(__bf16* __restrict__ S) {
  const int row = blockIdx.x;  // 0..16383 = b*2048 + i
  const int i = row & 2047;
  __bf16* s = S + (long long)row * 2048;
  const int Lpad = (i + 256) & ~255;  // round_up(i+1, 256): PV reads this far
  const int t = threadIdx.x;
  const int j0 = t * 8;
  const int wid = t >> 6, lane = t & 63;
  const bool active = j0 < Lpad;

  float v[8];
  float mymax = -3.0e38f;
  if (active) {
    bf16x8 x = *(const bf16x8*)(s + j0);
#pragma unroll
    for (int e = 0; e < 8; e++) {
      float f = (float)x[e];
      v[e] = ((j0 + e) <= i) ? f : -3.0e38f;
      mymax = fmaxf(mymax, v[e]);
    }
  }
  float mw = mymax;
#pragma unroll
  for (int o = 32; o >= 1; o >>= 1) mw = fmaxf(mw, __shfl_xor(mw, o));
  __shared__ float redm[4];
  __shared__ float reds[4];
  if (lane == 0) redm[wid] = mw;
  __syncthreads();
  const float m = fmaxf(fmaxf(redm[0], redm[1]), fmaxf(redm[2], redm[3]));

  float e8[8];
  float mysum = 0.0f;
  if (active) {
#pragma unroll
    for (int e = 0; e < 8; e++) {
      float ev = ((j0 + e) <= i) ? __expf(v[e] - m) : 0.0f;
      e8[e] = ev;
      mysum += ev;
    }
  } else {
#pragma unroll
    for (int e = 0; e < 8; e++) e8[e] = 0.0f;
  }
  float sw = mysum;
#pragma unroll
  for (int o = 32; o >= 1; o >>= 1) sw += __shfl_xor(sw, o);
  if (lane == 0) reds[wid] = sw;
  __syncthreads();
  const float l = reds[0] + reds[1] + reds[2] + reds[3];
  const float rl = 1.0f / l;
  if (active) {
    bf16x8 o;
#pragma unroll
    for (int e = 0; e < 8; e++) o[e] = (__bf16)(e8[e] * rl);
    *(bf16x8*)(s + j0) = o;
  }
}

// ---------------------------------------------------------------- launch
extern "C" void kernel_launch(void* const* d_in, const int* in_sizes, int n_in,
                              void* d_out, int out_size, void* d_ws, size_t ws_size,
                              hipStream_t stream) {
  const float* y  = (const float*)d_in[0];
  const float* Wq = (const float*)d_in[1];
  const float* bq = (const float*)d_in[2];
  const float* Wk = (const float*)d_in[3];
  const float* bk = (const float*)d_in[4];
  const float* Wv = (const float*)d_in[5];
  const float* bv = (const float*)d_in[6];
  const float* Wo = (const float*)d_in[7];
  const float* bo = (const float*)d_in[8];

  char* ws = (char*)d_ws;
  __bf16* Xb   = (__bf16*)(ws + 0);            // 16384x1024 bf16 X   (32 MiB) [ctx after PV]
  __bf16* Wt   = (__bf16*)(ws + 33554432);     // 4 x [1024][1024] bf16 W^T (8 MiB)
  float*  bqkv = (float*)(ws + 41943040);      // 3x1024 fp32
  __bf16* Qb   = (__bf16*)(ws + 41955328);     // 8x2048x1024 Q       (32 MiB)
  __bf16* Kb   = (__bf16*)(ws + 75509760);     // 8x2048x1024 K       (32 MiB)
  __bf16* Vt   = (__bf16*)(ws + 109064192);    // 8 x [1024][2048] V^T (32 MiB)
  __bf16* Sb   = (__bf16*)(ws + 142618624);    // 8x2048x2048 S/P (ends at 209,727,488)
  __bf16* ctx  = (__bf16*)(ws + 0);            // PV output reuses Xb region

  if (ws_size < 209727488u) return;

  convert_bf16_k<<<2048, 256, 0, stream>>>(y, Xb, 2097152);
  pack_bias_k<<<12, 256, 0, stream>>>(bq, bk, bv, bqkv);
  transpose_w_k<<<dim3(32, 32, 4), dim3(32, 8), 0, stream>>>(Wq, Wk, Wv, Wo, Wt);

  // Fused QKV projection: 128x256-tile 2-wg/CU kernel (conflict-free swizzle),
  // z-split (z0->Qb scaled, z1->Kb, z2->Vt via LDS transpose). A-stripe, z slowest.
  gemm2w<2><<<dim3(128, 4, 3), 512, 0, stream>>>(
      Xb, 1024, 0LL, Wt, 1024, 1048576LL,
      Qb, 1024, 16777216LL, bqkv, 1024, 0.03125f, 32, Vt);

  // S = Q @ K^T per batch: packed lower-triangle launch (36 tiles x 8 batches)
  gemm8<0, 2><<<dim3(36, 1, 8), 512, 0, stream>>>(
      Qb, 1024, 2097152LL, Kb, 1024, 2097152LL,
      Sb, 2048, 4194304LL, nullptr, 0, 1.0f, 16, 0, nullptr);

  // causal softmax in place (zero-pads to 256-block edge)
  softmax_rows<<<16384, 256, 0, stream>>>(Sb);

  // ctx = P @ V : kt = 4*(br+1) causal truncation; batch-local swizzle
  gemm8<0, 3><<<dim3(8, 4, 8), 512, 0, stream>>>(
      Sb, 2048, 4194304LL, Vt, 2048, 2097152LL,
      ctx, 1024, 2097152LL, nullptr, 0, 1.0f, 4, 4, nullptr);

  // out = ctx @ Wo + bo (fp32 epilogue to d_out), gemm8 A-stripe (round-4 best)
  gemm8<1, 1><<<dim3(64, 4, 1), 512, 0, stream>>>(
      ctx, 1024, 0LL, Wt + 3 * 1048576, 1024, 0LL,
      d_out, 1024, 0LL, bo, 0, 1.0f, 16, 0, nullptr);
}

// Round 9
// 315.195 us; speedup vs baseline: 1.0868x; 1.0449x over previous
//
#include <hip/hip_runtime.h>

typedef __attribute__((ext_vector_type(8))) __bf16 bf16x8;
typedef __attribute__((ext_vector_type(4))) float f32x4;
typedef __attribute__((ext_vector_type(4))) float f4;
typedef __attribute__((ext_vector_type(4))) unsigned short ushort4_t;

__device__ inline void gload16(const void* g, void* l) {
  __builtin_amdgcn_global_load_lds(
      (const __attribute__((address_space(1))) unsigned int*)g,
      (__attribute__((address_space(3))) unsigned int*)l, 16, 0, 0);
}

// ---------------------------------------------------------------- converts
__global__ void convert_bf16_k(const float* __restrict__ in, __bf16* __restrict__ out, int n8) {
  int i = blockIdx.x * blockDim.x + threadIdx.x;
  int stride = gridDim.x * blockDim.x;
  for (; i < n8; i += stride) {
    f4 a = ((const f4*)in)[2 * (long long)i];
    f4 b = ((const f4*)in)[2 * (long long)i + 1];
    bf16x8 o;
#pragma unroll
    for (int e = 0; e < 4; e++) { o[e] = (__bf16)a[e]; o[e + 4] = (__bf16)b[e]; }
    ((bf16x8*)out)[i] = o;
  }
}

__global__ void pack_bias_k(const float* __restrict__ bq, const float* __restrict__ bk,
                            const float* __restrict__ bv, float* __restrict__ out) {
  int i = blockIdx.x * 256 + threadIdx.x;
  if (i >= 3072) return;
  const float* src = (i < 1024) ? bq : (i < 2048) ? bk : bv;
  out[i] = src[i & 1023];
}

// W[k][n] fp32 -> Wt[n][k] bf16, 4 weights via z
__global__ void transpose_w_k(const float* __restrict__ W0, const float* __restrict__ W1,
                              const float* __restrict__ W2, const float* __restrict__ W3,
                              __bf16* __restrict__ out) {
  int z = blockIdx.z;
  const float* W = (z == 0) ? W0 : (z == 1) ? W1 : (z == 2) ? W2 : W3;
  __bf16* O = out + (long long)z * 1048576;
  __shared__ float tile[32][33];
  int tx = threadIdx.x, ty = threadIdx.y;
  int n0 = blockIdx.x * 32, k0 = blockIdx.y * 32;
#pragma unroll
  for (int i = 0; i < 4; i++)
    tile[ty + i * 8][tx] = W[(long long)(k0 + ty + i * 8) * 1024 + n0 + tx];
  __syncthreads();
#pragma unroll
  for (int i = 0; i < 4; i++)
    O[(long long)(n0 + ty + i * 8) * 1024 + k0 + tx] = (__bf16)tile[tx][ty + i * 8];
}

#define FENCE asm volatile("" ::: "memory")

// ---------------------------------------------------------------- gemm8: 256x256 tile, BK=64, 8-phase
// (round-4 form). Used for S-gemm (SWZ=2) and out-proj (SWZ=1).
// LDS 160 KiB: A triple-buffered + B double-buffered, XOR-swizzled (row&7)<<4.
// A(kk+2) issued during tile kk; B(kk+2) overwrites-behind. ENDPB vmcnt(8).

#define LOADA(BASE, MIB)                                                       \
  _Pragma("unroll") for (int mi = 0; mi < 4; mi++)                             \
      _Pragma("unroll") for (int kh = 0; kh < 2; kh++) {                       \
    int row = ((MIB) + mi) * 16 + ln15;                                        \
    int pb = (row * 128 + (kh * 32 + kq * 8) * 2) ^ ((row & 7) << 4);          \
    a[mi][kh] = *(const bf16x8*)((BASE) + pb);                                 \
  }

#define LOADB(BASE, NIB)                                                       \
  _Pragma("unroll") for (int ni = 0; ni < 2; ni++)                             \
      _Pragma("unroll") for (int kh = 0; kh < 2; kh++) {                       \
    int row = brow0 + ((NIB) + ni) * 16 + ln15;                                \
    int pb = (row * 128 + (kh * 32 + kq * 8) * 2) ^ ((row & 7) << 4);          \
    b[(NIB) + ni][kh] = *(const bf16x8*)((BASE) + pb);                         \
  }

#define MFMAQ(MI0, NI0)                                                        \
  _Pragma("unroll") for (int mi = 0; mi < 4; mi++)                             \
      _Pragma("unroll") for (int ni = 0; ni < 2; ni++)                         \
          _Pragma("unroll") for (int kh = 0; kh < 2; kh++)                     \
              acc[(MI0) + mi][(NI0) + ni] =                                    \
      __builtin_amdgcn_mfma_f32_16x16x32_bf16(a[mi][kh], b[(NI0) + ni][kh],    \
                                              acc[(MI0) + mi][(NI0) + ni], 0, 0, 0);

#define BARW                                           \
  FENCE;                                               \
  __builtin_amdgcn_s_barrier();                        \
  FENCE;                                               \
  __builtin_amdgcn_s_setprio(1);

#define ENDP                                           \
  __builtin_amdgcn_s_setprio(0);                       \
  FENCE;                                               \
  __builtin_amdgcn_s_barrier();                        \
  FENCE;

#define ENDPB                                          \
  __builtin_amdgcn_s_setprio(0);                       \
  asm volatile("s_waitcnt vmcnt(8)" ::: "memory");     \
  __builtin_amdgcn_s_barrier();                        \
  FENCE;

template <int OUT, int SWZ>
__global__ __launch_bounds__(512, 2) void gemm8(
    const __bf16* __restrict__ A0, int lda, long long sAz,
    const __bf16* __restrict__ B0, int ldb, long long sBz,
    void* __restrict__ C0v, int ldc, long long sCz,
    const float* __restrict__ bias0, int sBiasZ,
    float scale_z0, int k_tiles_base, int k_tiles_per_br,
    __bf16* __restrict__ vt_out) {
  int br, bc, z;
  {
    const int lin = (blockIdx.z * gridDim.y + blockIdx.y) * gridDim.x + blockIdx.x;
    if (SWZ == 1) {
      // A-stripe: XCD q -> br in [8q,8q+8), br fastest; then bc; then z.
      const int q = lin & 7, c = lin >> 3;
      br = q * 8 + (c & 7);
      const int rest = c >> 3;
      const int nby = gridDim.y;
      bc = rest % nby;
      z = rest / nby;
    } else if (SWZ == 2) {
      // packed lower triangle, one batch per XCD; c in [0,36) -> (br,bc) bc<=br
      const int q = lin & 7, c = lin >> 3;
      z = q;
      int b0 = (int)((sqrtf((float)(8 * c + 1)) - 1.0f) * 0.5f);
      int c0 = c - ((b0 * (b0 + 1)) >> 1);
      if (c0 < 0) { b0--; c0 = c - ((b0 * (b0 + 1)) >> 1); }
      if (c0 > b0) { b0++; c0 = c - ((b0 * (b0 + 1)) >> 1); }
      br = b0;
      bc = c0;
    } else if (SWZ == 3) {
      // batch-local: XCD q = batch q; c -> (br fast, bc)
      const int q = lin & 7, c = lin >> 3;
      z = q;
      br = c & 7;
      bc = c >> 3;
    } else {
      const int nbx = gridDim.x, nby = gridDim.y;
      const int nwg = nbx * nby * gridDim.z;
      const int cpx = nwg >> 3;
      const int swz = (lin & 7) * cpx + (lin >> 3);
      br = swz % nbx;
      const int tmp = swz / nbx;
      bc = tmp % nby;
      z = tmp / nby;
    }
  }
  const int kt = k_tiles_base + k_tiles_per_br * br;  // >= 2

  // 160 KiB LDS: A bufs at 0,16384,32768 (elems); B bufs at 49152,65536
  __shared__ __align__(16) __bf16 lds[81920];

  const int t = threadIdx.x, w = t >> 6, lane = t & 63;
  const int wm = w >> 2, wn = w & 3;
  const int ln15 = lane & 15, kq = lane >> 4;
  const int bh = wn >> 1, brow0 = (wn & 1) * 64;

  const __bf16* A = A0 + (long long)z * sAz + (long long)br * 256 * lda;
  const __bf16* B = B0 + (long long)z * sBz + (long long)bc * 256 * ldb;

  int r0s[2], c0s[2];
#pragma unroll
  for (int i = 0; i < 2; i++) {
    int o = i * 8192 + t * 16;
    int lo = o ^ (((o >> 7) & 7) << 4);
    r0s[i] = lo >> 7;
    c0s[i] = (lo & 127) >> 1;
  }
  const __bf16 *sA0[2], *sA1[2], *sB0[2], *sB1[2];
#pragma unroll
  for (int i = 0; i < 2; i++) {
    sA0[i] = A + (long long)r0s[i] * lda + c0s[i];
    sA1[i] = A + (long long)(r0s[i] + 128) * lda + c0s[i];
    sB0[i] = B + (long long)r0s[i] * ldb + c0s[i];
    sB1[i] = B + (long long)(r0s[i] + 128) * ldb + c0s[i];
  }

  auto stg = [&](const __bf16* const* src, __bf16* lbase, int g) {
    int kc = g < kt ? g : kt - 1;  // clamped dup keeps per-iter issue count = 8
#pragma unroll
    for (int i = 0; i < 2; i++)
      gload16(src[i] + kc * 64, lbase + i * 4096 + w * 512);
  };

  f32x4 acc[8][4] = {};
  bf16x8 a[4][2], b[4][2];

  stg(sA0, lds, 0);
  stg(sA1, lds + 8192, 0);
  stg(sB0, lds + 49152, 0);
  stg(sB1, lds + 49152 + 8192, 0);
  stg(sA0, lds + 16384, 1);
  stg(sA1, lds + 16384 + 8192, 1);
  stg(sB0, lds + 65536, 1);
  stg(sB1, lds + 65536 + 8192, 1);
  asm volatile("s_waitcnt vmcnt(8)" ::: "memory");
  __builtin_amdgcn_s_barrier();
  FENCE;

  int ap = 0, ad = 2;
  for (int kk = 0; kk < kt; kk++) {
    __bf16* Ab = lds + ap * 16384;
    __bf16* Bb = lds + 49152 + (kk & 1) * 16384;
    __bf16* Ad = lds + ad * 16384;
    __bf16* Bd = Bb;
    const char* Aw = (const char*)(Ab + wm * 8192);
    const char* Bw = (const char*)(Bb + bh * 8192);
    LOADA(Aw, 0) LOADB(Bw, 0)
    stg(sA0, Ad, kk + 2);
    BARW MFMAQ(0, 0) ENDP
    LOADB(Bw, 2)
    stg(sA1, Ad + 8192, kk + 2);
    BARW MFMAQ(0, 2) ENDP
    LOADA(Aw, 4)
    stg(sB0, Bd, kk + 2);
    BARW MFMAQ(4, 2) ENDP
    stg(sB1, Bd + 8192, kk + 2);
    BARW MFMAQ(4, 0) ENDPB
    ap = (ap == 2) ? 0 : ap + 1;
    ad = (ad == 2) ? 0 : ad + 1;
  }

  {
    const int row0 = br * 256 + wm * 128 + kq * 4;
    const int col0 = bc * 256 + wn * 64 + ln15;
    const float scale = (z == 0) ? scale_z0 : 1.0f;
    const float* bias = bias0 ? (bias0 + (long long)z * sBiasZ) : nullptr;
#pragma unroll
    for (int mi = 0; mi < 8; mi++) {
#pragma unroll
      for (int ni = 0; ni < 4; ni++) {
        const int rr = row0 + mi * 16;
        const int cc = col0 + ni * 16;
        const float bb = bias ? bias[cc] : 0.0f;
#pragma unroll
        for (int j = 0; j < 4; j++) {
          float v = (acc[mi][ni][j] + bb) * scale;
          long long off = (long long)z * sCz + (long long)(rr + j) * ldc + cc;
          if (OUT == 1)
            ((float*)C0v)[off] = v;
          else
            ((__bf16*)C0v)[off] = (__bf16)v;
        }
      }
    }
  }
  (void)vt_out;
}

// ---------------------------------------------------------------- gemm2w: 128x256 tile, BK=32, 2 wgs/CU
// 8 waves (2M x 4N), per-wave 64x64 (acc[4][4]; 60 VGPR -> 4 waves/SIMD).
// LDS 72 KiB: A triple-buffered (3 x 8 KiB) + B triple-buffered (3 x 16 KiB).
// Swizzle ^(((row>>1)&3)<<4): free 2-way bank aliasing (262K conflicts, R8).
// 2-deep prefetch, vmcnt(3) at tile end. 2 wgs/CU: one wg's stalls covered by
// the other wg's MFMA (m114).
// OUT: 0 = bf16 C; 1 = f32 C; 2 = fused QKV z-routing (z<2 scalar bf16 C,
//      z==2 V LDS-transposed into vt_out[b][d][t]).
// SWZ: 0 = A-stripe (XCD q owns br in [16q,16q+16), br fastest; needs nbx=128)
//      4 = PV complementary-pair: 512 wgs; wg j and j+256 share (z,bc) with
//          br_j + br_{j+256} = 15 -> per-CU slot sum == 68 under round-robin
//          dispatch (exact balance of the causal kt skew). z = j&7 keeps each
//          XCD on one batch (Vt slice 4 MiB L2-resident).
template <int OUT, int SWZ>
__global__ __launch_bounds__(512, 4) void gemm2w(
    const __bf16* __restrict__ A0, int lda, long long sAz,
    const __bf16* __restrict__ B0, int ldb, long long sBz,
    void* __restrict__ C0v, int ldc, long long sCz,
    const float* __restrict__ bias0, int sBiasZ,
    float scale_z0, int k_tiles_base, int k_tiles_per_br,
    __bf16* __restrict__ vt_out) {
  int br, bc, z;
  {
    const int lin = (blockIdx.z * gridDim.y + blockIdx.y) * gridDim.x + blockIdx.x;
    if (SWZ == 4) {
      // complementary-pair causal schedule (gridDim = 512,1,1)
      z = lin & 7;
      const int r = (lin >> 3) & 7;
      bc = (lin >> 6) & 3;
      const int half = lin >> 8;  // 0: long half (br 8..15), 1: short (7..0)
      br = half ? (7 - r) : (8 + r);
    } else {
      const int q = lin & 7, c = lin >> 3;
      br = q * 16 + (c & 15);
      const int rest = c >> 4;
      const int nby = gridDim.y;
      bc = rest % nby;
      z = rest / nby;
    }
  }
  const int kt = k_tiles_base + k_tiles_per_br * br;  // >= 2 (BK=32 units)

  // 72 KiB LDS: A bufs at 0,4096,8192 (elems); B bufs at 12288,20480,28672
  __shared__ __align__(16) __bf16 lds[36864];

  const int t = threadIdx.x, w = t >> 6, lane = t & 63;
  const int wm = w >> 2, wn = w & 3;
  const int ln15 = lane & 15, kq = lane >> 4;

  const __bf16* A = A0 + (long long)z * sAz + (long long)br * 128 * lda;
  const __bf16* B = B0 + (long long)z * sBz + (long long)bc * 256 * ldb;

  // staging src (dest linear o = t*16 bytes, inverse-swizzled; 64B rows;
  // swz touches bits 4-5, row = o>>6 unchanged -> lo = o ^ (((o>>7)&3)<<4))
  const __bf16* sA;
  const __bf16* sB[2];
  {
    int o = t * 16;
    int lo = o ^ (((o >> 7) & 3) << 4);
    sA = A + (long long)(lo >> 6) * lda + ((lo & 63) >> 1);
  }
#pragma unroll
  for (int i = 0; i < 2; i++) {
    int o = i * 8192 + t * 16;
    int lo = o ^ (((o >> 7) & 3) << 4);
    sB[i] = B + (long long)(lo >> 6) * ldb + ((lo & 63) >> 1);
  }

  auto stgA = [&](int buf, int g) {
    int kc = g < kt ? g : kt - 1;
    gload16(sA + kc * 32, lds + buf * 4096 + w * 512);
  };
  auto stgB = [&](int buf, int g) {
    int kc = g < kt ? g : kt - 1;
#pragma unroll
    for (int i = 0; i < 2; i++)
      gload16(sB[i] + kc * 32, lds + 12288 + buf * 8192 + i * 4096 + w * 512);
  };

  f32x4 acc[4][4] = {};
  bf16x8 a[4], b[4];

  // prologue: tiles 0 and 1 (3 loads each); vmcnt(3) -> tile 0 resident
  stgA(0, 0); stgB(0, 0);
  stgA(1, 1); stgB(1, 1);
  asm volatile("s_waitcnt vmcnt(3)" ::: "memory");
  __builtin_amdgcn_s_barrier();
  FENCE;

  int cb = 0, db = 2;
  for (int kk = 0; kk < kt; kk++) {
    const char* Ab = (const char*)(lds + cb * 4096);
    const char* Bb = (const char*)(lds + 12288 + cb * 8192);
#pragma unroll
    for (int mi = 0; mi < 4; mi++) {
      int row = wm * 64 + mi * 16 + ln15;
      int pb = (row * 64 + kq * 16) ^ (((row >> 1) & 3) << 4);
      a[mi] = *(const bf16x8*)(Ab + pb);
    }
#pragma unroll
    for (int ni = 0; ni < 4; ni++) {
      int row = wn * 64 + ni * 16 + ln15;
      int pb = (row * 64 + kq * 16) ^ (((row >> 1) & 3) << 4);
      b[ni] = *(const bf16x8*)(Bb + pb);
    }
    stgA(db, kk + 2);
    stgB(db, kk + 2);
    FENCE;
    __builtin_amdgcn_s_barrier();
    FENCE;
    __builtin_amdgcn_s_setprio(1);
#pragma unroll
    for (int mi = 0; mi < 4; mi++)
#pragma unroll
      for (int ni = 0; ni < 4; ni++)
        acc[mi][ni] = __builtin_amdgcn_mfma_f32_16x16x32_bf16(
            a[mi], b[ni], acc[mi][ni], 0, 0, 0);
    __builtin_amdgcn_s_setprio(0);
    asm volatile("s_waitcnt vmcnt(3)" ::: "memory");
    __builtin_amdgcn_s_barrier();
    FENCE;
    cb = (cb == 2) ? 0 : cb + 1;
    db = (db == 2) ? 0 : db + 1;
  }
  // drain clamped-dup prefetches before LDS reuse / exit (stale DMA safety)
  asm volatile("s_waitcnt vmcnt(0)" ::: "memory");

  if (OUT == 2 && z == 2) {
    // V: stage 128(t) x 256(d) tile into LDS as [d][t] (256B rows, XOR
    // ((d&7)<<4) -> 2-way), then coalesced 16B stores into vt_out[b][d][t].
    __syncthreads();
    char* lb = (char*)lds;
#pragma unroll
    for (int mi = 0; mi < 4; mi++) {
#pragma unroll
      for (int ni = 0; ni < 4; ni++) {
        const int d = wn * 64 + ni * 16 + ln15;
        const int tl = wm * 64 + kq * 4 + mi * 16;
        const float bb = bias0[2048 + bc * 256 + d];
        ushort4_t p;
#pragma unroll
        for (int j = 0; j < 4; j++) {
          union { __bf16 h; unsigned short u; } cv;
          cv.h = (__bf16)(acc[mi][ni][j] + bb);
          p[j] = cv.u;
        }
        int byte = (d * 256 + tl * 2) ^ ((d & 7) << 4);
        *(ushort4_t*)(lb + byte) = p;
      }
    }
    __syncthreads();
    const int bz = br >> 4;
    const int t0 = (br & 15) * 128;
    __bf16* vbase = vt_out + (long long)bz * 2097152 +
                    (long long)(bc * 256) * 2048 + t0;
#pragma unroll
    for (int it = 0; it < 8; it++) {
      int idx = it * 512 + t;  // 16B units, 4096 total (256 d x 16)
      int d = idx >> 4, tc = idx & 15;
      int byte = (d * 256 + tc * 16) ^ ((d & 7) << 4);
      bf16x8 vv = *(const bf16x8*)(lb + byte);
      *(bf16x8*)(vbase + (long long)d * 2048 + tc * 8) = vv;
    }
  } else {
    const int row0 = br * 128 + wm * 64 + kq * 4;
    const int col0 = bc * 256 + wn * 64 + ln15;
    const float scale = (z == 0) ? scale_z0 : 1.0f;
    const float* bias = bias0 ? (bias0 + (long long)z * sBiasZ) : nullptr;
#pragma unroll
    for (int mi = 0; mi < 4; mi++) {
#pragma unroll
      for (int ni = 0; ni < 4; ni++) {
        const int rr = row0 + mi * 16;
        const int cc = col0 + ni * 16;
        const float bb = bias ? bias[cc] : 0.0f;
#pragma unroll
        for (int j = 0; j < 4; j++) {
          float v = (acc[mi][ni][j] + bb) * scale;
          long long off = (long long)z * sCz + (long long)(rr + j) * ldc + cc;
          if (OUT == 1)
            ((float*)C0v)[off] = v;
          else
            ((__bf16*)C0v)[off] = (__bf16)v;
        }
      }
    }
  }
}

// ---------------------------------------------------------------- softmax (causal, in-place on S bf16)
__global__ __launch_bounds__(256) void softmax_rows(__bf16* __restrict__ S) {
  const int row = blockIdx.x;  // 0..16383 = b*2048 + i
  const int i = row & 2047;
  __bf16* s = S + (long long)row * 2048;
  const int Lpad = (i + 256) & ~255;  // round_up(i+1, 256): PV reads this far
  const int t = threadIdx.x;
  const int j0 = t * 8;
  const int wid = t >> 6, lane = t & 63;
  const bool active = j0 < Lpad;

  float v[8];
  float mymax = -3.0e38f;
  if (active) {
    bf16x8 x = *(const bf16x8*)(s + j0);
#pragma unroll
    for (int e = 0; e < 8; e++) {
      float f = (float)x[e];
      v[e] = ((j0 + e) <= i) ? f : -3.0e38f;
      mymax = fmaxf(mymax, v[e]);
    }
  }
  float mw = mymax;
#pragma unroll
  for (int o = 32; o >= 1; o >>= 1) mw = fmaxf(mw, __shfl_xor(mw, o));
  __shared__ float redm[4];
  __shared__ float reds[4];
  if (lane == 0) redm[wid] = mw;
  __syncthreads();
  const float m = fmaxf(fmaxf(redm[0], redm[1]), fmaxf(redm[2], redm[3]));

  float e8[8];
  float mysum = 0.0f;
  if (active) {
#pragma unroll
    for (int e = 0; e < 8; e++) {
      float ev = ((j0 + e) <= i) ? __expf(v[e] - m) : 0.0f;
      e8[e] = ev;
      mysum += ev;
    }
  } else {
#pragma unroll
    for (int e = 0; e < 8; e++) e8[e] = 0.0f;
  }
  float sw = mysum;
#pragma unroll
  for (int o = 32; o >= 1; o >>= 1) sw += __shfl_xor(sw, o);
  if (lane == 0) reds[wid] = sw;
  __syncthreads();
  const float l = reds[0] + reds[1] + reds[2] + reds[3];
  const float rl = 1.0f / l;
  if (active) {
    bf16x8 o;
#pragma unroll
    for (int e = 0; e < 8; e++) o[e] = (__bf16)(e8[e] * rl);
    *(bf16x8*)(s + j0) = o;
  }
}

// ---------------------------------------------------------------- launch
extern "C" void kernel_launch(void* const* d_in, const int* in_sizes, int n_in,
                              void* d_out, int out_size, void* d_ws, size_t ws_size,
                              hipStream_t stream) {
  const float* y  = (const float*)d_in[0];
  const float* Wq = (const float*)d_in[1];
  const float* bq = (const float*)d_in[2];
  const float* Wk = (const float*)d_in[3];
  const float* bk = (const float*)d_in[4];
  const float* Wv = (const float*)d_in[5];
  const float* bv = (const float*)d_in[6];
  const float* Wo = (const float*)d_in[7];
  const float* bo = (const float*)d_in[8];

  char* ws = (char*)d_ws;
  __bf16* Xb   = (__bf16*)(ws + 0);            // 16384x1024 bf16 X   (32 MiB) [ctx after PV]
  __bf16* Wt   = (__bf16*)(ws + 33554432);     // 4 x [1024][1024] bf16 W^T (8 MiB)
  float*  bqkv = (float*)(ws + 41943040);      // 3x1024 fp32
  __bf16* Qb   = (__bf16*)(ws + 41955328);     // 8x2048x1024 Q       (32 MiB)
  __bf16* Kb   = (__bf16*)(ws + 75509760);     // 8x2048x1024 K       (32 MiB)
  __bf16* Vt   = (__bf16*)(ws + 109064192);    // 8 x [1024][2048] V^T (32 MiB)
  __bf16* Sb   = (__bf16*)(ws + 142618624);    // 8x2048x2048 S/P (ends at 209,727,488)
  __bf16* ctx  = (__bf16*)(ws + 0);            // PV output reuses Xb region

  if (ws_size < 209727488u) return;

  convert_bf16_k<<<2048, 256, 0, stream>>>(y, Xb, 2097152);
  pack_bias_k<<<12, 256, 0, stream>>>(bq, bk, bv, bqkv);
  transpose_w_k<<<dim3(32, 32, 4), dim3(32, 8), 0, stream>>>(Wq, Wk, Wv, Wo, Wt);

  // Fused QKV projection: 128x256-tile 2-wg/CU kernel (conflict-free swizzle),
  // z-split (z0->Qb scaled, z1->Kb, z2->Vt via LDS transpose). A-stripe, z slowest.
  gemm2w<2, 0><<<dim3(128, 4, 3), 512, 0, stream>>>(
      Xb, 1024, 0LL, Wt, 1024, 1048576LL,
      Qb, 1024, 16777216LL, bqkv, 1024, 0.03125f, 32, 0, Vt);

  // S = Q @ K^T per batch: packed lower-triangle launch (36 tiles x 8 batches)
  gemm8<0, 2><<<dim3(36, 1, 8), 512, 0, stream>>>(
      Qb, 1024, 2097152LL, Kb, 1024, 2097152LL,
      Sb, 2048, 4194304LL, nullptr, 0, 1.0f, 16, 0, nullptr);

  // causal softmax in place (zero-pads to 256-block edge)
  softmax_rows<<<16384, 256, 0, stream>>>(Sb);

  // ctx = P @ V : 128x256-tile gemm2w, kt = 4(br+1) BK32 causal truncation,
  // complementary-pair schedule (512 wgs, per-CU slot sum == 68, 2 wgs/CU).
  gemm2w<0, 4><<<dim3(512, 1, 1), 512, 0, stream>>>(
      Sb, 2048, 4194304LL, Vt, 2048, 2097152LL,
      ctx, 1024, 2097152LL, nullptr, 0, 1.0f, 4, 4, nullptr);

  // out = ctx @ Wo + bo (fp32 epilogue to d_out), gemm8 A-stripe (round-4 best)
  gemm8<1, 1><<<dim3(64, 4, 1), 512, 0, stream>>>(
      ctx, 1024, 0LL, Wt + 3 * 1048576, 1024, 0LL,
      d_out, 1024, 0LL, bo, 0, 1.0f, 16, 0, nullptr);
}

// Round 10
// 298.600 us; speedup vs baseline: 1.1472x; 1.0556x over previous
//
#include <hip/hip_runtime.h>

typedef __attribute__((ext_vector_type(8))) __bf16 bf16x8;
typedef __attribute__((ext_vector_type(4))) float f32x4;
typedef __attribute__((ext_vector_type(4))) float f4;
typedef __attribute__((ext_vector_type(4))) unsigned short ushort4_t;

__device__ inline void gload16(const void* g, void* l) {
  __builtin_amdgcn_global_load_lds(
      (const __attribute__((address_space(1))) unsigned int*)g,
      (__attribute__((address_space(3))) unsigned int*)l, 16, 0, 0);
}

#define FENCE asm volatile("" ::: "memory")

// ---------------------------------------------------------------- prep: convert + W-transpose + bias pack
// One launch (6156 blocks x 256 thr), blockIdx.x-routed:
//   [0,2048)    : X fp32 -> bf16 (grid-stride, 16B/lane)
//   [2048,6144) : W[k][n] fp32 -> Wt[n][k] bf16, 4 weights (1024 blocks each)
//   [6144,6156) : bias pack 3x1024 fp32
__global__ __launch_bounds__(256) void prep_k(
    const float* __restrict__ y,
    const float* __restrict__ Wq, const float* __restrict__ Wk,
    const float* __restrict__ Wv, const float* __restrict__ Wo,
    const float* __restrict__ bq, const float* __restrict__ bk,
    const float* __restrict__ bv,
    __bf16* __restrict__ Xb, __bf16* __restrict__ Wt, float* __restrict__ bqkv) {
  __shared__ float tile[32][33];
  const int bid = blockIdx.x, t = threadIdx.x;
  if (bid < 2048) {
    for (int i = bid * 256 + t; i < 2097152; i += 524288) {
      f4 a = ((const f4*)y)[2 * (long long)i];
      f4 b = ((const f4*)y)[2 * (long long)i + 1];
      bf16x8 o;
#pragma unroll
      for (int e = 0; e < 4; e++) { o[e] = (__bf16)a[e]; o[e + 4] = (__bf16)b[e]; }
      ((bf16x8*)Xb)[i] = o;
    }
  } else if (bid < 6144) {
    const int idx = bid - 2048;
    const int z = idx >> 10, rem = idx & 1023;
    const int bx = rem & 31, by = rem >> 5;
    const float* W = (z == 0) ? Wq : (z == 1) ? Wk : (z == 2) ? Wv : Wo;
    __bf16* O = Wt + (long long)z * 1048576;
    const int tx = t & 31, ty = t >> 5;
    const int n0 = bx * 32, k0 = by * 32;
#pragma unroll
    for (int i = 0; i < 4; i++)
      tile[ty + i * 8][tx] = W[(long long)(k0 + ty + i * 8) * 1024 + n0 + tx];
    __syncthreads();
#pragma unroll
    for (int i = 0; i < 4; i++)
      O[(long long)(n0 + ty + i * 8) * 1024 + k0 + tx] = (__bf16)tile[tx][ty + i * 8];
  } else {
    const int i = (bid - 6144) * 256 + t;
    if (i < 3072) {
      const float* src = (i < 1024) ? bq : (i < 2048) ? bk : bv;
      bqkv[i] = src[i & 1023];
    }
  }
}

// ---------------------------------------------------------------- gemm8: 256x256 tile, BK=64, 8-phase
// (round-4 form). Used for out-proj (SWZ=1 A-stripe).
// LDS 160 KiB: A triple-buffered + B double-buffered, XOR-swizzled (row&7)<<4.
// A(kk+2) issued during tile kk; B(kk+2) overwrites-behind. ENDPB vmcnt(8).

#define LOADA(BASE, MIB)                                                       \
  _Pragma("unroll") for (int mi = 0; mi < 4; mi++)                             \
      _Pragma("unroll") for (int kh = 0; kh < 2; kh++) {                       \
    int row = ((MIB) + mi) * 16 + ln15;                                        \
    int pb = (row * 128 + (kh * 32 + kq * 8) * 2) ^ ((row & 7) << 4);          \
    a[mi][kh] = *(const bf16x8*)((BASE) + pb);                                 \
  }

#define LOADB(BASE, NIB)                                                       \
  _Pragma("unroll") for (int ni = 0; ni < 2; ni++)                             \
      _Pragma("unroll") for (int kh = 0; kh < 2; kh++) {                       \
    int row = brow0 + ((NIB) + ni) * 16 + ln15;                                \
    int pb = (row * 128 + (kh * 32 + kq * 8) * 2) ^ ((row & 7) << 4);          \
    b[(NIB) + ni][kh] = *(const bf16x8*)((BASE) + pb);                         \
  }

#define MFMAQ(MI0, NI0)                                                        \
  _Pragma("unroll") for (int mi = 0; mi < 4; mi++)                             \
      _Pragma("unroll") for (int ni = 0; ni < 2; ni++)                         \
          _Pragma("unroll") for (int kh = 0; kh < 2; kh++)                     \
              acc[(MI0) + mi][(NI0) + ni] =                                    \
      __builtin_amdgcn_mfma_f32_16x16x32_bf16(a[mi][kh], b[(NI0) + ni][kh],    \
                                              acc[(MI0) + mi][(NI0) + ni], 0, 0, 0);

#define BARW                                           \
  FENCE;                                               \
  __builtin_amdgcn_s_barrier();                        \
  FENCE;                                               \
  __builtin_amdgcn_s_setprio(1);

#define ENDP                                           \
  __builtin_amdgcn_s_setprio(0);                       \
  FENCE;                                               \
  __builtin_amdgcn_s_barrier();                        \
  FENCE;

#define ENDPB                                          \
  __builtin_amdgcn_s_setprio(0);                       \
  asm volatile("s_waitcnt vmcnt(8)" ::: "memory");     \
  __builtin_amdgcn_s_barrier();                        \
  FENCE;

template <int OUT, int SWZ>
__global__ __launch_bounds__(512, 2) void gemm8(
    const __bf16* __restrict__ A0, int lda, long long sAz,
    const __bf16* __restrict__ B0, int ldb, long long sBz,
    void* __restrict__ C0v, int ldc, long long sCz,
    const float* __restrict__ bias0, int sBiasZ,
    float scale_z0, int k_tiles_base, int k_tiles_per_br) {
  int br, bc, z;
  {
    const int lin = (blockIdx.z * gridDim.y + blockIdx.y) * gridDim.x + blockIdx.x;
    if (SWZ == 1) {
      // A-stripe: XCD q -> br in [8q,8q+8), br fastest; then bc; then z.
      const int q = lin & 7, c = lin >> 3;
      br = q * 8 + (c & 7);
      const int rest = c >> 3;
      const int nby = gridDim.y;
      bc = rest % nby;
      z = rest / nby;
    } else {
      const int nbx = gridDim.x, nby = gridDim.y;
      const int nwg = nbx * nby * gridDim.z;
      const int cpx = nwg >> 3;
      const int swz = (lin & 7) * cpx + (lin >> 3);
      br = swz % nbx;
      const int tmp = swz / nbx;
      bc = tmp % nby;
      z = tmp / nby;
    }
  }
  const int kt = k_tiles_base + k_tiles_per_br * br;  // >= 2

  // 160 KiB LDS: A bufs at 0,16384,32768 (elems); B bufs at 49152,65536
  __shared__ __align__(16) __bf16 lds[81920];

  const int t = threadIdx.x, w = t >> 6, lane = t & 63;
  const int wm = w >> 2, wn = w & 3;
  const int ln15 = lane & 15, kq = lane >> 4;
  const int bh = wn >> 1, brow0 = (wn & 1) * 64;

  const __bf16* A = A0 + (long long)z * sAz + (long long)br * 256 * lda;
  const __bf16* B = B0 + (long long)z * sBz + (long long)bc * 256 * ldb;

  int r0s[2], c0s[2];
#pragma unroll
  for (int i = 0; i < 2; i++) {
    int o = i * 8192 + t * 16;
    int lo = o ^ (((o >> 7) & 7) << 4);
    r0s[i] = lo >> 7;
    c0s[i] = (lo & 127) >> 1;
  }
  const __bf16 *sA0[2], *sA1[2], *sB0[2], *sB1[2];
#pragma unroll
  for (int i = 0; i < 2; i++) {
    sA0[i] = A + (long long)r0s[i] * lda + c0s[i];
    sA1[i] = A + (long long)(r0s[i] + 128) * lda + c0s[i];
    sB0[i] = B + (long long)r0s[i] * ldb + c0s[i];
    sB1[i] = B + (long long)(r0s[i] + 128) * ldb + c0s[i];
  }

  auto stg = [&](const __bf16* const* src, __bf16* lbase, int g) {
    int kc = g < kt ? g : kt - 1;  // clamped dup keeps per-iter issue count = 8
#pragma unroll
    for (int i = 0; i < 2; i++)
      gload16(src[i] + kc * 64, lbase + i * 4096 + w * 512);
  };

  f32x4 acc[8][4] = {};
  bf16x8 a[4][2], b[4][2];

  stg(sA0, lds, 0);
  stg(sA1, lds + 8192, 0);
  stg(sB0, lds + 49152, 0);
  stg(sB1, lds + 49152 + 8192, 0);
  stg(sA0, lds + 16384, 1);
  stg(sA1, lds + 16384 + 8192, 1);
  stg(sB0, lds + 65536, 1);
  stg(sB1, lds + 65536 + 8192, 1);
  asm volatile("s_waitcnt vmcnt(8)" ::: "memory");
  __builtin_amdgcn_s_barrier();
  FENCE;

  int ap = 0, ad = 2;
  for (int kk = 0; kk < kt; kk++) {
    __bf16* Ab = lds + ap * 16384;
    __bf16* Bb = lds + 49152 + (kk & 1) * 16384;
    __bf16* Ad = lds + ad * 16384;
    __bf16* Bd = Bb;
    const char* Aw = (const char*)(Ab + wm * 8192);
    const char* Bw = (const char*)(Bb + bh * 8192);
    LOADA(Aw, 0) LOADB(Bw, 0)
    stg(sA0, Ad, kk + 2);
    BARW MFMAQ(0, 0) ENDP
    LOADB(Bw, 2)
    stg(sA1, Ad + 8192, kk + 2);
    BARW MFMAQ(0, 2) ENDP
    LOADA(Aw, 4)
    stg(sB0, Bd, kk + 2);
    BARW MFMAQ(4, 2) ENDP
    stg(sB1, Bd + 8192, kk + 2);
    BARW MFMAQ(4, 0) ENDPB
    ap = (ap == 2) ? 0 : ap + 1;
    ad = (ad == 2) ? 0 : ad + 1;
  }

  {
    const int row0 = br * 256 + wm * 128 + kq * 4;
    const int col0 = bc * 256 + wn * 64 + ln15;
    const float scale = (z == 0) ? scale_z0 : 1.0f;
    const float* bias = bias0 ? (bias0 + (long long)z * sBiasZ) : nullptr;
#pragma unroll
    for (int mi = 0; mi < 8; mi++) {
#pragma unroll
      for (int ni = 0; ni < 4; ni++) {
        const int rr = row0 + mi * 16;
        const int cc = col0 + ni * 16;
        const float bb = bias ? bias[cc] : 0.0f;
#pragma unroll
        for (int j = 0; j < 4; j++) {
          float v = (acc[mi][ni][j] + bb) * scale;
          long long off = (long long)z * sCz + (long long)(rr + j) * ldc + cc;
          if (OUT == 1)
            ((float*)C0v)[off] = v;
          else
            ((__bf16*)C0v)[off] = (__bf16)v;
        }
      }
    }
  }
}

// ---------------------------------------------------------------- gemm2w: 128x256 tile, BK=32, 2 wgs/CU
// 8 waves (2M x 4N), per-wave 64x64 (acc[4][4]; 60 VGPR -> 4 waves/SIMD).
// LDS 72 KiB: A triple-buffered (3 x 8 KiB) + B triple-buffered (3 x 16 KiB).
// Swizzle ^(((row>>1)&3)<<4): free 2-way bank aliasing (262K conflicts, R8).
// 2-deep prefetch, vmcnt(3) at tile end. 2 wgs/CU: one wg's stalls covered by
// the other wg's MFMA (m114). Measured rate 0.61 us per BK32-slot per CU (R9).
// OUT: 0 = bf16 C; 1 = f32 C; 2 = fused QKV z-routing (z<2 scalar bf16 C,
//      z==2 V LDS-transposed into vt_out[b][d][t]).
// SWZ: 0 = A-stripe (XCD q owns br in [16q,16q+16), br fastest; needs nbx=128)
//      4 = PV complementary-pair: 512 wgs; wg j and j+256 share (z,bc) with
//          br_j + br_{j+256} = 15 -> per-CU slot sum == 68 (exact balance).
//      5 = S-gemm causal: 576 wgs; z = XCD = batch (K-slice L2-local);
//          c in [0,72) -> (br,bc): row-pair m = rows {2m,2m+1}, each m+1 tiles;
//          m from sqrt(4c+1), r = c - m(m+1); br = 2m + (r>=m+1), bc = r%(m+1).
template <int OUT, int SWZ>
__global__ __launch_bounds__(512, 4) void gemm2w(
    const __bf16* __restrict__ A0, int lda, long long sAz,
    const __bf16* __restrict__ B0, int ldb, long long sBz,
    void* __restrict__ C0v, int ldc, long long sCz,
    const float* __restrict__ bias0, int sBiasZ,
    float scale_z0, int k_tiles_base, int k_tiles_per_br,
    __bf16* __restrict__ vt_out) {
  int br, bc, z;
  {
    const int lin = (blockIdx.z * gridDim.y + blockIdx.y) * gridDim.x + blockIdx.x;
    if (SWZ == 4) {
      // complementary-pair causal schedule (gridDim = 512,1,1)
      z = lin & 7;
      const int r = (lin >> 3) & 7;
      bc = (lin >> 6) & 3;
      const int half = lin >> 8;  // 0: long half (br 8..15), 1: short (7..0)
      br = half ? (7 - r) : (8 + r);
    } else if (SWZ == 5) {
      // packed causal 128x256 tiles (gridDim = 576,1,1)
      z = lin & 7;
      const int c = lin >> 3;  // 0..71
      int m = (int)((sqrtf((float)(4 * c + 1)) - 1.0f) * 0.5f);
      if (c < m * (m + 1)) m--;
      if (c >= (m + 1) * (m + 2)) m++;
      const int r = c - m * (m + 1);  // 0..2m+1
      if (r >= m + 1) { br = 2 * m + 1; bc = r - (m + 1); }
      else { br = 2 * m; bc = r; }
    } else {
      const int q = lin & 7, c = lin >> 3;
      br = q * 16 + (c & 15);
      const int rest = c >> 4;
      const int nby = gridDim.y;
      bc = rest % nby;
      z = rest / nby;
    }
  }
  const int kt = k_tiles_base + k_tiles_per_br * br;  // >= 2 (BK=32 units)

  // 72 KiB LDS: A bufs at 0,4096,8192 (elems); B bufs at 12288,20480,28672
  __shared__ __align__(16) __bf16 lds[36864];

  const int t = threadIdx.x, w = t >> 6, lane = t & 63;
  const int wm = w >> 2, wn = w & 3;
  const int ln15 = lane & 15, kq = lane >> 4;

  const __bf16* A = A0 + (long long)z * sAz + (long long)br * 128 * lda;
  const __bf16* B = B0 + (long long)z * sBz + (long long)bc * 256 * ldb;

  // staging src (dest linear o = t*16 bytes, inverse-swizzled; 64B rows;
  // swz touches bits 4-5, row = o>>6 unchanged -> lo = o ^ (((o>>7)&3)<<4))
  const __bf16* sA;
  const __bf16* sB[2];
  {
    int o = t * 16;
    int lo = o ^ (((o >> 7) & 3) << 4);
    sA = A + (long long)(lo >> 6) * lda + ((lo & 63) >> 1);
  }
#pragma unroll
  for (int i = 0; i < 2; i++) {
    int o = i * 8192 + t * 16;
    int lo = o ^ (((o >> 7) & 3) << 4);
    sB[i] = B + (long long)(lo >> 6) * ldb + ((lo & 63) >> 1);
  }

  auto stgA = [&](int buf, int g) {
    int kc = g < kt ? g : kt - 1;
    gload16(sA + kc * 32, lds + buf * 4096 + w * 512);
  };
  auto stgB = [&](int buf, int g) {
    int kc = g < kt ? g : kt - 1;
#pragma unroll
    for (int i = 0; i < 2; i++)
      gload16(sB[i] + kc * 32, lds + 12288 + buf * 8192 + i * 4096 + w * 512);
  };

  f32x4 acc[4][4] = {};
  bf16x8 a[4], b[4];

  // prologue: tiles 0 and 1 (3 loads each); vmcnt(3) -> tile 0 resident
  stgA(0, 0); stgB(0, 0);
  stgA(1, 1); stgB(1, 1);
  asm volatile("s_waitcnt vmcnt(3)" ::: "memory");
  __builtin_amdgcn_s_barrier();
  FENCE;

  int cb = 0, db = 2;
  for (int kk = 0; kk < kt; kk++) {
    const char* Ab = (const char*)(lds + cb * 4096);
    const char* Bb = (const char*)(lds + 12288 + cb * 8192);
#pragma unroll
    for (int mi = 0; mi < 4; mi++) {
      int row = wm * 64 + mi * 16 + ln15;
      int pb = (row * 64 + kq * 16) ^ (((row >> 1) & 3) << 4);
      a[mi] = *(const bf16x8*)(Ab + pb);
    }
#pragma unroll
    for (int ni = 0; ni < 4; ni++) {
      int row = wn * 64 + ni * 16 + ln15;
      int pb = (row * 64 + kq * 16) ^ (((row >> 1) & 3) << 4);
      b[ni] = *(const bf16x8*)(Bb + pb);
    }
    stgA(db, kk + 2);
    stgB(db, kk + 2);
    FENCE;
    __builtin_amdgcn_s_barrier();
    FENCE;
    __builtin_amdgcn_s_setprio(1);
#pragma unroll
    for (int mi = 0; mi < 4; mi++)
#pragma unroll
      for (int ni = 0; ni < 4; ni++)
        acc[mi][ni] = __builtin_amdgcn_mfma_f32_16x16x32_bf16(
            a[mi], b[ni], acc[mi][ni], 0, 0, 0);
    __builtin_amdgcn_s_setprio(0);
    asm volatile("s_waitcnt vmcnt(3)" ::: "memory");
    __builtin_amdgcn_s_barrier();
    FENCE;
    cb = (cb == 2) ? 0 : cb + 1;
    db = (db == 2) ? 0 : db + 1;
  }
  // drain clamped-dup prefetches before LDS reuse / exit (stale DMA safety)
  asm volatile("s_waitcnt vmcnt(0)" ::: "memory");

  if (OUT == 2 && z == 2) {
    // V: stage 128(t) x 256(d) tile into LDS as [d][t] (256B rows, XOR
    // ((d&7)<<4) -> 2-way), then coalesced 16B stores into vt_out[b][d][t].
    __syncthreads();
    char* lb = (char*)lds;
#pragma unroll
    for (int mi = 0; mi < 4; mi++) {
#pragma unroll
      for (int ni = 0; ni < 4; ni++) {
        const int d = wn * 64 + ni * 16 + ln15;
        const int tl = wm * 64 + kq * 4 + mi * 16;
        const float bb = bias0[2048 + bc * 256 + d];
        ushort4_t p;
#pragma unroll
        for (int j = 0; j < 4; j++) {
          union { __bf16 h; unsigned short u; } cv;
          cv.h = (__bf16)(acc[mi][ni][j] + bb);
          p[j] = cv.u;
        }
        int byte = (d * 256 + tl * 2) ^ ((d & 7) << 4);
        *(ushort4_t*)(lb + byte) = p;
      }
    }
    __syncthreads();
    const int bz = br >> 4;
    const int t0 = (br & 15) * 128;
    __bf16* vbase = vt_out + (long long)bz * 2097152 +
                    (long long)(bc * 256) * 2048 + t0;
#pragma unroll
    for (int it = 0; it < 8; it++) {
      int idx = it * 512 + t;  // 16B units, 4096 total (256 d x 16)
      int d = idx >> 4, tc = idx & 15;
      int byte = (d * 256 + tc * 16) ^ ((d & 7) << 4);
      bf16x8 vv = *(const bf16x8*)(lb + byte);
      *(bf16x8*)(vbase + (long long)d * 2048 + tc * 8) = vv;
    }
  } else {
    const int row0 = br * 128 + wm * 64 + kq * 4;
    const int col0 = bc * 256 + wn * 64 + ln15;
    const float scale = (z == 0) ? scale_z0 : 1.0f;
    const float* bias = bias0 ? (bias0 + (long long)z * sBiasZ) : nullptr;
#pragma unroll
    for (int mi = 0; mi < 4; mi++) {
#pragma unroll
      for (int ni = 0; ni < 4; ni++) {
        const int rr = row0 + mi * 16;
        const int cc = col0 + ni * 16;
        const float bb = bias ? bias[cc] : 0.0f;
#pragma unroll
        for (int j = 0; j < 4; j++) {
          float v = (acc[mi][ni][j] + bb) * scale;
          long long off = (long long)z * sCz + (long long)(rr + j) * ldc + cc;
          if (OUT == 1)
            ((float*)C0v)[off] = v;
          else
            ((__bf16*)C0v)[off] = (__bf16)v;
        }
      }
    }
  }
}

// ---------------------------------------------------------------- softmax (causal, in-place on S bf16)
__global__ __launch_bounds__(256) void softmax_rows(__bf16* __restrict__ S) {
  const int row = blockIdx.x;  // 0..16383 = b*2048 + i
  const int i = row & 2047;
  __bf16* s = S + (long long)row * 2048;
  const int Lpad = (i + 128) & ~127;  // round_up(i+1,128): PV reads exactly this far
  const int t = threadIdx.x;
  const int j0 = t * 8;
  const int wid = t >> 6, lane = t & 63;
  const bool active = j0 < Lpad;

  float v[8];
  float mymax = -3.0e38f;
  if (active) {
    bf16x8 x = *(const bf16x8*)(s + j0);
#pragma unroll
    for (int e = 0; e < 8; e++) {
      float f = (float)x[e];
      v[e] = ((j0 + e) <= i) ? f : -3.0e38f;
      mymax = fmaxf(mymax, v[e]);
    }
  }
  float mw = mymax;
#pragma unroll
  for (int o = 32; o >= 1; o >>= 1) mw = fmaxf(mw, __shfl_xor(mw, o));
  __shared__ float redm[4];
  __shared__ float reds[4];
  if (lane == 0) redm[wid] = mw;
  __syncthreads();
  const float m = fmaxf(fmaxf(redm[0], redm[1]), fmaxf(redm[2], redm[3]));

  float e8[8];
  float mysum = 0.0f;
  if (active) {
#pragma unroll
    for (int e = 0; e < 8; e++) {
      float ev = ((j0 + e) <= i) ? __expf(v[e] - m) : 0.0f;
      e8[e] = ev;
      mysum += ev;
    }
  } else {
#pragma unroll
    for (int e = 0; e < 8; e++) e8[e] = 0.0f;
  }
  float sw = mysum;
#pragma unroll
  for (int o = 32; o >= 1; o >>= 1) sw += __shfl_xor(sw, o);
  if (lane == 0) reds[wid] = sw;
  __syncthreads();
  const float l = reds[0] + reds[1] + reds[2] + reds[3];
  const float rl = 1.0f / l;
  if (active) {
    bf16x8 o;
#pragma unroll
    for (int e = 0; e < 8; e++) o[e] = (__bf16)(e8[e] * rl);
    *(bf16x8*)(s + j0) = o;
  }
}

// ---------------------------------------------------------------- launch
extern "C" void kernel_launch(void* const* d_in, const int* in_sizes, int n_in,
                              void* d_out, int out_size, void* d_ws, size_t ws_size,
                              hipStream_t stream) {
  const float* y  = (const float*)d_in[0];
  const float* Wq = (const float*)d_in[1];
  const float* bq = (const float*)d_in[2];
  const float* Wk = (const float*)d_in[3];
  const float* bk = (const float*)d_in[4];
  const float* Wv = (const float*)d_in[5];
  const float* bv = (const float*)d_in[6];
  const float* Wo = (const float*)d_in[7];
  const float* bo = (const float*)d_in[8];

  char* ws = (char*)d_ws;
  __bf16* Xb   = (__bf16*)(ws + 0);            // 16384x1024 bf16 X   (32 MiB) [ctx after PV]
  __bf16* Wt   = (__bf16*)(ws + 33554432);     // 4 x [1024][1024] bf16 W^T (8 MiB)
  float*  bqkv = (float*)(ws + 41943040);      // 3x1024 fp32
  __bf16* Qb   = (__bf16*)(ws + 41955328);     // 8x2048x1024 Q       (32 MiB)
  __bf16* Kb   = (__bf16*)(ws + 75509760);     // 8x2048x1024 K       (32 MiB)
  __bf16* Vt   = (__bf16*)(ws + 109064192);    // 8 x [1024][2048] V^T (32 MiB)
  __bf16* Sb   = (__bf16*)(ws + 142618624);    // 8x2048x2048 S/P (ends at 209,727,488)
  __bf16* ctx  = (__bf16*)(ws + 0);            // PV output reuses Xb region

  if (ws_size < 209727488u) return;

  // fused prep: X->bf16, W transposes, bias pack (one launch)
  prep_k<<<6156, 256, 0, stream>>>(y, Wq, Wk, Wv, Wo, bq, bk, bv, Xb, Wt, bqkv);

  // Fused QKV projection: 128x256-tile 2-wg/CU kernel (conflict-free swizzle),
  // z-split (z0->Qb scaled, z1->Kb, z2->Vt via LDS transpose). A-stripe, z slowest.
  gemm2w<2, 0><<<dim3(128, 4, 3), 512, 0, stream>>>(
      Xb, 1024, 0LL, Wt, 1024, 1048576LL,
      Qb, 1024, 16777216LL, bqkv, 1024, 0.03125f, 32, 0, Vt);

  // S = Q @ K^T: 128x256 causal tiles, 576 wgs at 2/CU (balanced TLP),
  // z = XCD = batch (K-slice 4 MiB L2-local).
  gemm2w<0, 5><<<dim3(576, 1, 1), 512, 0, stream>>>(
      Qb, 1024, 2097152LL, Kb, 1024, 2097152LL,
      Sb, 2048, 4194304LL, nullptr, 0, 1.0f, 32, 0, nullptr);

  // causal softmax in place (zero-pads to 128-block edge = PV read extent)
  softmax_rows<<<16384, 256, 0, stream>>>(Sb);

  // ctx = P @ V : 128x256-tile gemm2w, kt = 4(br+1) BK32 causal truncation,
  // complementary-pair schedule (512 wgs, per-CU slot sum == 68, 2 wgs/CU).
  gemm2w<0, 4><<<dim3(512, 1, 1), 512, 0, stream>>>(
      Sb, 2048, 4194304LL, Vt, 2048, 2097152LL,
      ctx, 1024, 2097152LL, nullptr, 0, 1.0f, 4, 4, nullptr);

  // out = ctx @ Wo + bo (fp32 epilogue to d_out), gemm8 A-stripe (round-4 best)
  gemm8<1, 1><<<dim3(64, 4, 1), 512, 0, stream>>>(
      ctx, 1024, 0LL, Wt + 3 * 1048576, 1024, 0LL,
      d_out, 1024, 0LL, bo, 0, 1.0f, 16, 0);
}